// Round 7
// baseline (198.406 us; speedup 1.0000x reference)
//
#include <hip/hip_runtime.h>

// CausalSelfAttention: B=4, T=2048, C=1024, H=16, hd=64
// cast->bf16, 256^2 8-wave pipelined GEMMs (counted-vmcnt, swizzled LDS),
// 32x32-MFMA swapped-QK^T flash attention

#define T_SEQ 2048
#define NB 4
#define NH 16
#define CDIM 1024
#define HD 64
#define BH (NB * NH)
#define QSCALE 0.1803368801111204f  // 0.125 * log2(e)

typedef float f32x4 __attribute__((ext_vector_type(4)));
typedef float f32x16 __attribute__((ext_vector_type(16)));
typedef __bf16 bf16x8 __attribute__((ext_vector_type(8)));
typedef unsigned short u16x8 __attribute__((ext_vector_type(8)));
typedef unsigned short u16x4 __attribute__((ext_vector_type(4)));

__device__ __forceinline__ unsigned short f2b(float f) {
    union { float f; unsigned u; } v; v.f = f;
    unsigned u = v.u;
    u += 0x7FFFu + ((u >> 16) & 1u);   // round-to-nearest-even
    return (unsigned short)(u >> 16);
}

__device__ __forceinline__ f32x4 fzero4() {
    f32x4 z; z[0] = 0.f; z[1] = 0.f; z[2] = 0.f; z[3] = 0.f; return z;
}

__device__ __forceinline__ f32x16 mfma32(bf16x8 a, bf16x8 b, f32x16 c) {
    return __builtin_amdgcn_mfma_f32_32x32x16_bf16(a, b, c, 0, 0, 0);
}

// async global->LDS, 16B/lane; LDS dest = wave-uniform base + lane*16 (HW rule)
__device__ __forceinline__ void gld16(const void* gp, void* lp) {
    __builtin_amdgcn_global_load_lds(
        (const __attribute__((address_space(1))) unsigned int*)gp,
        (__attribute__((address_space(3))) unsigned int*)lp, 16, 0, 0);
}

#define VMCNT2 do { asm volatile("s_waitcnt vmcnt(2)" ::: "memory"); __builtin_amdgcn_sched_barrier(0); } while (0)
#define VMCNT0 do { asm volatile("s_waitcnt vmcnt(0)" ::: "memory"); __builtin_amdgcn_sched_barrier(0); } while (0)
#define LGKM0  do { asm volatile("s_waitcnt lgkmcnt(0)" ::: "memory"); __builtin_amdgcn_sched_barrier(0); } while (0)
#define BARRIER do { asm volatile("" ::: "memory"); __builtin_amdgcn_s_barrier(); __builtin_amdgcn_sched_barrier(0); } while (0)

// ---------------- prep: fp32 -> bf16 cast ----------------
__global__ __launch_bounds__(256) void cast_f32_bf16_kernel(
        const float* __restrict__ in, unsigned short* __restrict__ out, int n8) {
    int i = blockIdx.x * 256 + threadIdx.x;
    int stride = gridDim.x * 256;
    for (; i < n8; i += stride) {
        const float4* p = reinterpret_cast<const float4*>(in) + (size_t)i * 2;
        float4 a = p[0], b = p[1];
        u16x8 o;
        o[0] = f2b(a.x); o[1] = f2b(a.y); o[2] = f2b(a.z); o[3] = f2b(a.w);
        o[4] = f2b(b.x); o[5] = f2b(b.y); o[6] = f2b(b.z); o[7] = f2b(b.w);
        *(reinterpret_cast<u16x8*>(out) + i) = o;
    }
}

// ---------------- prep: transpose + cast [R][C] f32 -> [C][R] bf16 ----------------
__global__ __launch_bounds__(256) void transpose_cast_kernel(
        const float* __restrict__ in, unsigned short* __restrict__ out, int R, int C) {
    __shared__ unsigned short tile[32][33];
    int tx = threadIdx.x, ty = threadIdx.y;
    int c0 = blockIdx.x * 32, r0 = blockIdx.y * 32;
    for (int rr = ty; rr < 32; rr += 8)
        tile[rr][tx] = f2b(in[(size_t)(r0 + rr) * C + c0 + tx]);
    __syncthreads();
    for (int rr = ty; rr < 32; rr += 8)
        out[(size_t)(c0 + rr) * R + r0 + tx] = tile[tx][rr];
}

// ---------------- 256^2 8-wave pipelined GEMM ----------------
// C[M][N] = A[M][K] @ Bt[N][K]^T + bias. BM=BN=256, BK=64, 512 thr (8 waves 2Mx4N).
// LDS 128KB: 2 slots x 4 chunks ([128][64] bf16, 16KB), XOR swizzle: 16B-slot ^= row&7.
// 4 phases/K-tile: {ds_read next quadrant || stage 1 chunk -> MFMA(16) -> lgkm0 -> s_barrier},
// vmcnt(2) once per K-tile (loads stay in flight across barriers).
// EPI=0: fp32 out. EPI=1: scatter q(*QSCALE)/k to [BH][T][HD], v to V^T [BH][HD][T].
template <int EPI>
__global__ __launch_bounds__(512, 2) void gemm256_kernel(
        const unsigned short* __restrict__ A, const unsigned short* __restrict__ Bt,
        const float* __restrict__ bias, float* __restrict__ outF,
        unsigned short* __restrict__ q_out, unsigned short* __restrict__ k_out,
        unsigned short* __restrict__ v_out, int M, int N, int K, int nbx) {
    __shared__ alignas(16) char smem[131072];

    int tid = threadIdx.x;
    int wid = tid >> 6, lane = tid & 63;
    int wm = wid >> 2, wn = wid & 3;
    int lc = lane & 15, g = lane >> 4;
    int g16 = g << 4;
    int bchunk = 2 + (wn >> 1);
    int bofs = (wn & 1) * 64;

    // bijective XCD swizzle (gridDim.x % 8 == 0)
    int id = blockIdx.x;
    int cpx = gridDim.x >> 3;
    int swz = (id & 7) * cpx + (id >> 3);
    int by = swz / nbx, bx = swz - by * nbx;
    int m0 = by * 256, n0 = bx * 256;

    f32x4 acc[8][4];
#pragma unroll
    for (int i = 0; i < 8; ++i)
#pragma unroll
        for (int j = 0; j < 4; ++j) acc[i][j] = fzero4();

    // staging addressing: lane covers row r8 = lane>>3 of an 8-row group,
    // source col pre-swizzled: slot' = (lane&7) ^ r8  (inverse of the read XOR)
    int r8 = lane >> 3;
    int scol = ((lane & 7) ^ r8) * 8;
    const unsigned short* Agl = A + (size_t)(m0 + r8) * K + scol;
    const unsigned short* Bgl = Bt + (size_t)(n0 + r8) * K + scol;

    // chunk c: 0=A rows[0,128), 1=A rows[128,256), 2=B rows[0,128), 3=B rows[128,256)
#define STAGE(SLOT, C, KT) do {                                                     \
        const unsigned short* gp_ = ((C) < 2 ? Agl : Bgl)                           \
            + (size_t)(((C) & 1) * 128) * K + (size_t)(KT) * 64;                    \
        char* lb_ = smem + ((((SLOT) * 4) + (C)) << 14) + (wid << 10);              \
        gld16(gp_ + (size_t)(wid * 8) * K, lb_);                                    \
        gld16(gp_ + (size_t)(64 + wid * 8) * K, lb_ + 8192);                        \
    } while (0)

    struct QSub { bf16x8 a[4][2]; bf16x8 b[2][2]; };
    QSub sub0, sub1;

    // read A/B fragments of quadrant (QM,QN) of the tile in SLOT (swizzled addressing)
#define LOADQ(DST, SLOT, QM, QN) do {                                               \
        const char* Ab_ = smem + ((((SLOT) * 4) + wm) << 14);                       \
        _Pragma("unroll")                                                           \
        for (int i_ = 0; i_ < 4; ++i_) {                                            \
            int row_ = ((QM) * 4 + i_) * 16 + lc;                                   \
            int rb_ = row_ << 7, r7_ = (row_ & 7) << 4;                             \
            DST.a[i_][0] = *(const bf16x8*)(Ab_ + rb_ + (g16 ^ r7_));               \
            DST.a[i_][1] = *(const bf16x8*)(Ab_ + rb_ + ((64 + g16) ^ r7_));        \
        }                                                                           \
        const char* Bb_ = smem + ((((SLOT) * 4) + bchunk) << 14);                   \
        _Pragma("unroll")                                                           \
        for (int i_ = 0; i_ < 2; ++i_) {                                            \
            int row_ = bofs + ((QN) * 2 + i_) * 16 + lc;                            \
            int rb_ = row_ << 7, r7_ = (row_ & 7) << 4;                             \
            DST.b[i_][0] = *(const bf16x8*)(Bb_ + rb_ + (g16 ^ r7_));               \
            DST.b[i_][1] = *(const bf16x8*)(Bb_ + rb_ + ((64 + g16) ^ r7_));        \
        }                                                                           \
    } while (0)

#define DOQ(SRC, QM, QN) do {                                                       \
        __builtin_amdgcn_s_setprio(1);                                              \
        _Pragma("unroll")                                                           \
        for (int i_ = 0; i_ < 4; ++i_)                                              \
            _Pragma("unroll")                                                       \
            for (int j_ = 0; j_ < 2; ++j_) {                                        \
                acc[(QM) * 4 + i_][(QN) * 2 + j_] =                                 \
                    __builtin_amdgcn_mfma_f32_16x16x32_bf16(                        \
                        SRC.a[i_][0], SRC.b[j_][0],                                 \
                        acc[(QM) * 4 + i_][(QN) * 2 + j_], 0, 0, 0);                \
                acc[(QM) * 4 + i_][(QN) * 2 + j_] =                                 \
                    __builtin_amdgcn_mfma_f32_16x16x32_bf16(                        \
                        SRC.a[i_][1], SRC.b[j_][1],                                 \
                        acc[(QM) * 4 + i_][(QN) * 2 + j_], 0, 0, 0);                \
            }                                                                       \
        __builtin_amdgcn_s_setprio(0);                                              \
    } while (0)

    int nt = K >> 6;  // K-tiles of 64

    // prologue: tile0 all 4 chunks + tile1's A0; confirm tile0, keep A0(1) in flight
    STAGE(0, 0, 0); STAGE(0, 1, 0); STAGE(0, 2, 0); STAGE(0, 3, 0);
    STAGE(1, 0, 1);
    VMCNT2;
    BARRIER;
    LOADQ(sub0, 0, 0, 0);

    for (int t = 0; t < nt; ++t) {
        int sl = t & 1, sl2 = sl ^ 1;
        bool more1 = (t + 1 < nt), more2 = (t + 2 < nt);
        // phase 0: compute q(0,0) from sub0; read q(0,1); stage A1(t+1)
        LOADQ(sub1, sl, 0, 1);
        if (more1) STAGE(sl2, 1, t + 1);
        DOQ(sub0, 0, 0);
        LGKM0; BARRIER;
        // phase 1: compute q(0,1); read q(1,0); stage B0(t+1)
        LOADQ(sub0, sl, 1, 0);
        if (more1) STAGE(sl2, 2, t + 1);
        DOQ(sub1, 0, 1);
        LGKM0; BARRIER;
        // phase 2: compute q(1,0); read q(1,1); stage B1(t+1)
        LOADQ(sub1, sl, 1, 1);
        if (more1) STAGE(sl2, 3, t + 1);
        DOQ(sub0, 1, 0);
        LGKM0; BARRIER;
        // phase 3: stage A0(t+2); vmcnt(2) confirms tile t+1; read q(0,0) of t+1; compute q(1,1)
        if (more2) { STAGE(sl, 0, t + 2); VMCNT2; } else { VMCNT0; }
        BARRIER;
        if (more1) LOADQ(sub0, sl2, 0, 0);
        DOQ(sub1, 1, 1);
        LGKM0; BARRIER;
    }
#undef STAGE
#undef LOADQ
#undef DOQ

    // epilogue: C/D 16x16 layout col=lc, row=g*4+i
#pragma unroll
    for (int fm = 0; fm < 8; ++fm) {
        int rowb = m0 + wm * 128 + fm * 16 + g * 4;
#pragma unroll
        for (int fn = 0; fn < 4; ++fn) {
            int col = n0 + wn * 64 + fn * 16 + lc;
            float bv = bias[col];
            if (EPI == 0) {
#pragma unroll
                for (int i = 0; i < 4; ++i)
                    outF[(size_t)(rowb + i) * N + col] = acc[fm][fn][i] + bv;
            } else {
                int which = col >> 10;
                int c = col & 1023;
                int h = c >> 6, d = c & 63;
                int bh_ = (rowb >> 11) * NH + h;
                int tl = rowb & 2047;
                if (which == 2) {
                    u16x4 vq;
#pragma unroll
                    for (int i = 0; i < 4; ++i) vq[i] = f2b(acc[fm][fn][i] + bv);
                    *(u16x4*)&v_out[(size_t)bh_ * (HD * T_SEQ) + (size_t)d * T_SEQ + tl] = vq;
                } else {
                    unsigned short* dst = which ? k_out : q_out;
                    float sc = which ? 1.0f : QSCALE;
#pragma unroll
                    for (int i = 0; i < 4; ++i)
                        dst[((size_t)bh_ * T_SEQ + tl + i) * HD + d] =
                            f2b((acc[fm][fn][i] + bv) * sc);
                }
            }
        }
    }
}

// ---------------- flash attention: 32x32 MFMA, swapped QK^T ----------------
// 1024 blocks x 256 thr (4 waves). Block = (head, qg): q-tiles qg*4 + wid (32 rows each).
// S^T = mfma(K,Q): lane owns q = lane&31 -> lane-local softmax + defer-max.
// KV dbuf in LDS (16KB/tile, XOR-swizzled), prefetch next kt, one barrier per kt.
__global__ __launch_bounds__(256, 4) void attn32_kernel(
        const unsigned short* __restrict__ Qb, const unsigned short* __restrict__ Kb,
        const unsigned short* __restrict__ Vt, unsigned short* __restrict__ Yb) {
    __shared__ alignas(16) char smem[32768];  // 2 x (K 8KB + V 8KB)

    int tid = threadIdx.x;
    int wid = tid >> 6, lane = tid & 63;
    int ql = lane & 31, hi = lane >> 5;
    int ql7 = ql & 7;

    // balanced XCD-aware mapping: id -> (bh, qg)
    int id = blockIdx.x;
    int x = id & 7;          // XCD
    int k = id >> 3;         // 0..127 within XCD
    int r = k >> 5;          // dispatch round 0..3
    int c = k & 31;
    int hh = 2 * r + (c >> 4);
    int j = c & 15;
    int qg = (r & 1) ? (15 - j) : j;
    int bh = x * 8 + hh;
    size_t hb = (size_t)bh * (T_SEQ * HD);

    int qt = qg * 4 + wid;            // this wave's 32-row q-tile
    int q0 = qt * 32;
    int ktMax = qt >> 1;              // last (diagonal) KV tile for this wave
    int ntB = 2 * qg + 2;             // block's KV tile count (max over waves)

    // persistent Q B-frag (col=q=ql, elems d = dstep*16 + hi*8 + e)
    bf16x8 qf[4];
    const unsigned short* Qp = Qb + hb + (size_t)(q0 + ql) * HD + hi * 8;
#pragma unroll
    for (int d = 0; d < 4; ++d) qf[d] = *(const bf16x8*)(Qp + d * 16);

    f32x16 zz;
#pragma unroll
    for (int rr = 0; rr < 16; ++rr) zz[rr] = 0.f;
    f32x16 o0 = zz, o1 = zz;
    float mi = -__builtin_inff(), li = 0.f;

    // staging: wave w covers K rows [16w,16w+16) and V rows [16w,16w+16)
    int r8 = lane >> 3;
    int sslot8 = ((lane & 7) ^ r8) * 8;  // pre-swizzled source slot
    const unsigned short* Kg = Kb + hb + (size_t)(wid * 16 + r8) * HD + sslot8;
    const unsigned short* Vg = Vt + hb + (size_t)(wid * 16 + r8) * T_SEQ + sslot8;

    // prologue: stage kt=0 into buf 0
    gld16(Kg, smem + wid * 2048);
    gld16(Kg + 8 * HD, smem + wid * 2048 + 1024);
    gld16(Vg, smem + 8192 + wid * 2048);
    gld16(Vg + 8 * T_SEQ, smem + 8192 + wid * 2048 + 1024);
    __syncthreads();

#define KF(K0, D) (*(const bf16x8*)&KB_[(((K0)*32 + ql) << 6) + ((((D)*2 + hi) ^ ql7) << 3)])
#define VF(DB, T) (*(const bf16x8*)&VB_[(((DB)*32 + ql) << 6) + ((((T)*2 + hi) ^ ql7) << 3)])

    for (int kt = 0; kt < ntB; ++kt) {
        int cur = kt & 1;
        if (kt + 1 < ntB) {  // prefetch next tile into other buffer
            char* nb = smem + (cur ^ 1) * 16384;
            gld16(Kg + (size_t)(kt + 1) * 64 * HD, nb + wid * 2048);
            gld16(Kg + (size_t)((kt + 1) * 64 + 8) * HD, nb + wid * 2048 + 1024);
            gld16(Vg + (kt + 1) * 64, nb + 8192 + wid * 2048);
            gld16(Vg + (kt + 1) * 64 + 8 * T_SEQ, nb + 8192 + wid * 2048 + 1024);
        }
        if (kt <= ktMax) {
            const unsigned short* KB_ = (const unsigned short*)(smem + cur * 16384);
            const unsigned short* VB_ = (const unsigned short*)(smem + cur * 16384 + 8192);
            int k0 = kt * 64;

            f32x16 s0_, s1_;
            __builtin_amdgcn_s_setprio(1);
            s0_ = mfma32(KF(0, 0), qf[0], zz);
            s0_ = mfma32(KF(0, 1), qf[1], s0_);
            s0_ = mfma32(KF(0, 2), qf[2], s0_);
            s0_ = mfma32(KF(0, 3), qf[3], s0_);
            s1_ = mfma32(KF(1, 0), qf[0], zz);
            s1_ = mfma32(KF(1, 1), qf[1], s1_);
            s1_ = mfma32(KF(1, 2), qf[2], s1_);
            s1_ = mfma32(KF(1, 3), qf[3], s1_);
            __builtin_amdgcn_s_setprio(0);

            if (kt == ktMax) {  // causal mask, diagonal tile only
                int qg_ = q0 + ql;
#pragma unroll
                for (int rr = 0; rr < 16; ++rr) {
                    int kof_ = k0 + 8 * (rr >> 2) + (rr & 3) + 4 * hi;
                    if (kof_ > qg_) s0_[rr] = -__builtin_inff();
                    if (kof_ + 32 > qg_) s1_[rr] = -__builtin_inff();
                }
            }

            // lane-local row max (exp2 domain; q pre-scaled by 0.125*log2e)
            float t_[8];
#pragma unroll
            for (int rr = 0; rr < 8; ++rr)
                t_[rr] = fmaxf(fmaxf(s0_[rr], s0_[rr + 8]), fmaxf(s1_[rr], s1_[rr + 8]));
#pragma unroll
            for (int rr = 0; rr < 4; ++rr) t_[rr] = fmaxf(t_[rr], t_[rr + 4]);
            float pm_ = fmaxf(fmaxf(t_[0], t_[1]), fmaxf(t_[2], t_[3]));
            pm_ = fmaxf(pm_, __shfl_xor(pm_, 32));

            float mn_ = mi;
            if (!__all((int)(pm_ <= mi + 8.f))) {  // defer-max: skip rescale if small
                mn_ = fmaxf(mi, pm_);
                float f_ = __builtin_amdgcn_exp2f(mi - mn_);
                mi = mn_;
                li *= f_;
                o0 *= f_;
                o1 *= f_;
            }
#pragma unroll
            for (int rr = 0; rr < 16; ++rr) {
                s0_[rr] = __builtin_amdgcn_exp2f(s0_[rr] - mn_);
                s1_[rr] = __builtin_amdgcn_exp2f(s1_[rr] - mn_);
            }
            float u_[8];
#pragma unroll
            for (int rr = 0; rr < 8; ++rr)
                u_[rr] = (s0_[rr] + s0_[rr + 8]) + (s1_[rr] + s1_[rr + 8]);
#pragma unroll
            for (int rr = 0; rr < 4; ++rr) u_[rr] += u_[rr + 4];
            float ps_ = (u_[0] + u_[1]) + (u_[2] + u_[3]);
            ps_ += __shfl_xor(ps_, 32);
            li += ps_;

            // P -> PV B-frag via cvt_pk + permlane32_swap, then O += V^T P^T
#pragma unroll
            for (int K0_ = 0; K0_ < 2; ++K0_) {
#pragma unroll
                for (int h2_ = 0; h2_ < 2; ++h2_) {
                    float e0_ = K0_ ? s1_[8 * h2_ + 0] : s0_[8 * h2_ + 0];
                    float e1_ = K0_ ? s1_[8 * h2_ + 1] : s0_[8 * h2_ + 1];
                    float e2_ = K0_ ? s1_[8 * h2_ + 2] : s0_[8 * h2_ + 2];
                    float e3_ = K0_ ? s1_[8 * h2_ + 3] : s0_[8 * h2_ + 3];
                    float e4_ = K0_ ? s1_[8 * h2_ + 4] : s0_[8 * h2_ + 4];
                    float e5_ = K0_ ? s1_[8 * h2_ + 5] : s0_[8 * h2_ + 5];
                    float e6_ = K0_ ? s1_[8 * h2_ + 6] : s0_[8 * h2_ + 6];
                    float e7_ = K0_ ? s1_[8 * h2_ + 7] : s0_[8 * h2_ + 7];
                    unsigned a_, b_, c_, d_;
                    asm("v_cvt_pk_bf16_f32 %0, %1, %2" : "=v"(a_) : "v"(e0_), "v"(e1_));
                    asm("v_cvt_pk_bf16_f32 %0, %1, %2" : "=v"(b_) : "v"(e2_), "v"(e3_));
                    asm("v_cvt_pk_bf16_f32 %0, %1, %2" : "=v"(c_) : "v"(e4_), "v"(e5_));
                    asm("v_cvt_pk_bf16_f32 %0, %1, %2" : "=v"(d_) : "v"(e6_), "v"(e7_));
                    asm("v_permlane32_swap_b32 %0, %1" : "+v"(a_), "+v"(c_));
                    asm("v_permlane32_swap_b32 %0, %1" : "+v"(b_), "+v"(d_));
                    union { unsigned u[4]; bf16x8 v; } pf_;
                    pf_.u[0] = a_; pf_.u[1] = b_; pf_.u[2] = c_; pf_.u[3] = d_;
                    __builtin_amdgcn_s_setprio(1);
                    o0 = mfma32(VF(0, K0_ * 2 + h2_), pf_.v, o0);
                    o1 = mfma32(VF(1, K0_ * 2 + h2_), pf_.v, o1);
                    __builtin_amdgcn_s_setprio(0);
                }
            }
        }
        __syncthreads();
    }
#undef KF
#undef VF

    // epilogue: O^T[d][q]: q = q0+ql, d = dblk*32 + 8a + i + 4hi
    int bb = bh >> 4, h = bh & 15;
    float iv = 1.0f / li;
#pragma unroll
    for (int dblk = 0; dblk < 2; ++dblk) {
#pragma unroll
        for (int a = 0; a < 4; ++a) {
            u16x4 wv;
#pragma unroll
            for (int i = 0; i < 4; ++i)
                wv[i] = f2b((dblk ? o1[4 * a + i] : o0[4 * a + i]) * iv);
            int dq = dblk * 32 + 8 * a + 4 * hi;
            *(u16x4*)&Yb[((size_t)(bb * T_SEQ + q0 + ql)) * CDIM + h * HD + dq] = wv;
        }
    }
}

// ---------------- launch ----------------
extern "C" void kernel_launch(void* const* d_in, const int* in_sizes, int n_in,
                              void* d_out, int out_size, void* d_ws, size_t ws_size,
                              hipStream_t stream) {
    const float* x      = (const float*)d_in[0];
    const float* w_attn = (const float*)d_in[1];
    const float* b_attn = (const float*)d_in[2];
    const float* w_proj = (const float*)d_in[3];
    const float* b_proj = (const float*)d_in[4];
    float* out = (float*)d_out;

    // workspace layout (bytes):
    //   0         xb  : x bf16 [8192][1024]         16,777,216  (reused as yb)
    //   16777216  wTa : w_attn^T bf16 [3072][1024]   6,291,456
    //   23068672  wTp : w_proj^T bf16 [1024][1024]   2,097,152
    //   25165824  qb  : [64][2048][64] bf16         16,777,216  (pre-scaled by QSCALE)
    //   41943040  kb  : [64][2048][64] bf16         16,777,216
    //   58720256  vTb : [64][64][2048] bf16         16,777,216  (V^T, written by GEMM1)
    char* ws = (char*)d_ws;
    unsigned short* xb  = (unsigned short*)(ws);
    unsigned short* wTa = (unsigned short*)(ws + 16777216);
    unsigned short* wTp = (unsigned short*)(ws + 23068672);
    unsigned short* qb  = (unsigned short*)(ws + 25165824);
    unsigned short* kb  = (unsigned short*)(ws + 41943040);
    unsigned short* vTb = (unsigned short*)(ws + 58720256);
    unsigned short* yb  = xb;  // alias: xb dead after GEMM1

    cast_f32_bf16_kernel<<<2048, 256, 0, stream>>>(x, xb, (NB * T_SEQ * CDIM) / 8);
    transpose_cast_kernel<<<dim3(3072 / 32, 1024 / 32), dim3(32, 8), 0, stream>>>(
        w_attn, wTa, 1024, 3072);
    transpose_cast_kernel<<<dim3(1024 / 32, 1024 / 32), dim3(32, 8), 0, stream>>>(
        w_proj, wTp, 1024, 1024);

    // QKV GEMM: 256^2 tiles, grid 12x32 = 384 blocks
    gemm256_kernel<1><<<dim3(384), 512, 0, stream>>>(
        xb, wTa, b_attn, nullptr, qb, kb, vTb, 8192, 3072, 1024, 12);

    // flash attention: 1024 balanced blocks x 4 waves
    attn32_kernel<<<dim3(1024), 256, 0, stream>>>(qb, kb, vTb, yb);

    // proj GEMM: 256^2 tiles, grid 4x32 = 128 blocks -> fp32 out
    gemm256_kernel<0><<<dim3(128), 512, 0, stream>>>(
        yb, wTp, b_proj, out, nullptr, nullptr, nullptr, 8192, 1024, 1024, 4);
}

// Round 8
// 176.928 us; speedup vs baseline: 1.1214x; 1.1214x over previous
//
#include <hip/hip_runtime.h>

// CausalSelfAttention: B=4, T=2048, C=1024, H=16, hd=64
// cast->bf16, QKV GEMM (256^2/BK=32, 8-wave, swizzled LDS, 2 blocks/CU),
// 32x32-MFMA swapped-QK^T flash attention, proj GEMM (proven 2-phase 128^2)

#define T_SEQ 2048
#define NB 4
#define NH 16
#define CDIM 1024
#define HD 64
#define BH (NB * NH)
#define QSCALE 0.1803368801111204f  // 0.125 * log2(e)

typedef float f32x4 __attribute__((ext_vector_type(4)));
typedef float f32x16 __attribute__((ext_vector_type(16)));
typedef __bf16 bf16x8 __attribute__((ext_vector_type(8)));
typedef unsigned short u16x8 __attribute__((ext_vector_type(8)));
typedef unsigned short u16x4 __attribute__((ext_vector_type(4)));

__device__ __forceinline__ unsigned short f2b(float f) {
    union { float f; unsigned u; } v; v.f = f;
    unsigned u = v.u;
    u += 0x7FFFu + ((u >> 16) & 1u);   // round-to-nearest-even
    return (unsigned short)(u >> 16);
}

__device__ __forceinline__ f32x4 fzero4() {
    f32x4 z; z[0] = 0.f; z[1] = 0.f; z[2] = 0.f; z[3] = 0.f; return z;
}

__device__ __forceinline__ f32x4 mfma16(bf16x8 a, bf16x8 b, f32x4 c) {
    return __builtin_amdgcn_mfma_f32_16x16x32_bf16(a, b, c, 0, 0, 0);
}

__device__ __forceinline__ f32x16 mfma32(bf16x8 a, bf16x8 b, f32x16 c) {
    return __builtin_amdgcn_mfma_f32_32x32x16_bf16(a, b, c, 0, 0, 0);
}

// async global->LDS, 16B/lane; LDS dest = wave-uniform base + lane*16 (HW rule)
__device__ __forceinline__ void gld16(const void* gp, void* lp) {
    __builtin_amdgcn_global_load_lds(
        (const __attribute__((address_space(1))) unsigned int*)gp,
        (__attribute__((address_space(3))) unsigned int*)lp, 16, 0, 0);
}

// ---------------- prep: fp32 -> bf16 cast ----------------
__global__ __launch_bounds__(256) void cast_f32_bf16_kernel(
        const float* __restrict__ in, unsigned short* __restrict__ out, int n8) {
    int i = blockIdx.x * 256 + threadIdx.x;
    int stride = gridDim.x * 256;
    for (; i < n8; i += stride) {
        const float4* p = reinterpret_cast<const float4*>(in) + (size_t)i * 2;
        float4 a = p[0], b = p[1];
        u16x8 o;
        o[0] = f2b(a.x); o[1] = f2b(a.y); o[2] = f2b(a.z); o[3] = f2b(a.w);
        o[4] = f2b(b.x); o[5] = f2b(b.y); o[6] = f2b(b.z); o[7] = f2b(b.w);
        *(reinterpret_cast<u16x8*>(out) + i) = o;
    }
}

// ---------------- prep: transpose + cast [R][C] f32 -> [C][R] bf16 ----------------
__global__ __launch_bounds__(256) void transpose_cast_kernel(
        const float* __restrict__ in, unsigned short* __restrict__ out, int R, int C) {
    __shared__ unsigned short tile[32][33];
    int tx = threadIdx.x, ty = threadIdx.y;
    int c0 = blockIdx.x * 32, r0 = blockIdx.y * 32;
    for (int rr = ty; rr < 32; rr += 8)
        tile[rr][tx] = f2b(in[(size_t)(r0 + rr) * C + c0 + tx]);
    __syncthreads();
    for (int rr = ty; rr < 32; rr += 8)
        out[(size_t)(c0 + rr) * R + r0 + tx] = tile[tx][rr];
}

// ---------------- QKV GEMM: 256^2 tile, BK=32, 8 waves, 2 blocks/CU ----------------
// C[M][N] = A[M][K] @ Bt[N][K]^T + bias, scatter q(*QSCALE)/k to [BH][T][HD], v to V^T.
// LDS 64KB: 2 slots x (A[256][32] + B[256][32]) bf16, 16B-slot swizzle s ^= (row>>1)&3
// (conflict-free reads: 16 lanes -> 8 bank-spans x 2-way). Staged via gld16 with
// inverse-swizzled global source. Per K-tile: 12 ds_read_b128, 32 MFMA, 1 syncthreads.
__global__ __launch_bounds__(512, 2) void gemm256_kernel(
        const unsigned short* __restrict__ A, const unsigned short* __restrict__ Bt,
        const float* __restrict__ bias,
        unsigned short* __restrict__ q_out, unsigned short* __restrict__ k_out,
        unsigned short* __restrict__ v_out, int M, int N, int K, int nbx) {
    __shared__ alignas(16) char smem[65536];

    int tid = threadIdx.x;
    int wid = tid >> 6, lane = tid & 63;
    int wm = wid >> 2, wn = wid & 3;   // wave tile: rows wm*128, cols wn*64
    int lc = lane & 15, g = lane >> 4;
    int gp = g ^ ((lc >> 1) & 3);      // physical 16B slot (row-dependent term is lane-constant)

    // bijective XCD swizzle (gridDim.x % 8 == 0)
    int id = blockIdx.x;
    int cpx = gridDim.x >> 3;
    int swz = (id & 7) * cpx + (id >> 3);
    int by = swz / nbx, bx = swz - by * nbx;
    int m0 = by * 256, n0 = bx * 256;

    f32x4 acc[8][4];
#pragma unroll
    for (int i = 0; i < 8; ++i)
#pragma unroll
        for (int j = 0; j < 4; ++j) acc[i][j] = fzero4();

    // staging: thread t covers phys LDS (row = t>>2 [+128 on 2nd gld16], slot = t&3);
    // global col pre-swizzled: 8 * ((t&3) ^ ((row>>1)&3))  [128 offset keeps (row>>1)&3]
    int srow = tid >> 2;
    int scol = ((tid & 3) ^ ((srow >> 1) & 3)) * 8;
    const unsigned short* Agl = A + (size_t)(m0 + srow) * K + scol;
    const unsigned short* Bgl = Bt + (size_t)(n0 + srow) * K + scol;

#define STAGE_A(SLOT, KT) do {                                   \
        const unsigned short* g_ = Agl + (size_t)(KT) * 32;      \
        char* l_ = smem + (SLOT) * 32768 + wid * 1024;           \
        gld16(g_, l_);                                           \
        gld16(g_ + (size_t)128 * K, l_ + 8192);                  \
    } while (0)
#define STAGE_B(SLOT, KT) do {                                   \
        const unsigned short* g_ = Bgl + (size_t)(KT) * 32;      \
        char* l_ = smem + (SLOT) * 32768 + 16384 + wid * 1024;   \
        gld16(g_, l_);                                           \
        gld16(g_ + (size_t)128 * K, l_ + 8192);                  \
    } while (0)

    // frag read offsets (within slot): A row r = wm*128 + fm*16 + lc -> r*64 + gp*16
    int aoff = (wm * 128 + lc) * 64 + gp * 16;           // + fm*1024
    int boff = 16384 + (wn * 64 + lc) * 64 + gp * 16;    // + fn*1024

    STAGE_A(0, 0); STAGE_B(0, 0);
    __syncthreads();

    int nt = K >> 5;
    for (int t = 0; t < nt; ++t) {
        const char* sb = smem + (t & 1) * 32768;
        bool more = (t + 1 < nt);
        int sl2 = (t & 1) ^ 1;

        // phase 0: read A0-3 + B0-3, stage A(t+1), MFMA fm 0-3
        bf16x8 a0[4], b0[4];
#pragma unroll
        for (int i = 0; i < 4; ++i) a0[i] = *(const bf16x8*)(sb + aoff + i * 1024);
#pragma unroll
        for (int j = 0; j < 4; ++j) b0[j] = *(const bf16x8*)(sb + boff + j * 1024);
        if (more) STAGE_A(sl2, t + 1);
        __builtin_amdgcn_s_setprio(1);
#pragma unroll
        for (int i = 0; i < 4; ++i)
#pragma unroll
            for (int j = 0; j < 4; ++j)
                acc[i][j] = mfma16(a0[i], b0[j], acc[i][j]);
        __builtin_amdgcn_s_setprio(0);

        // phase 1: read A4-7 (B reused), stage B(t+1), MFMA fm 4-7
        bf16x8 a1[4];
#pragma unroll
        for (int i = 0; i < 4; ++i) a1[i] = *(const bf16x8*)(sb + aoff + (4 + i) * 1024);
        if (more) STAGE_B(sl2, t + 1);
        __builtin_amdgcn_s_setprio(1);
#pragma unroll
        for (int i = 0; i < 4; ++i)
#pragma unroll
            for (int j = 0; j < 4; ++j)
                acc[4 + i][j] = mfma16(a1[i], b0[j], acc[4 + i][j]);
        __builtin_amdgcn_s_setprio(0);

        __syncthreads();  // drains vmcnt (stages) + lgkm; slot swap
    }
#undef STAGE_A
#undef STAGE_B

    // epilogue: scatter q (scaled), k row-major; v transposed per head
#pragma unroll
    for (int fm = 0; fm < 8; ++fm) {
        int rowb = m0 + wm * 128 + fm * 16 + g * 4;
#pragma unroll
        for (int fn = 0; fn < 4; ++fn) {
            int col = n0 + wn * 64 + fn * 16 + lc;
            float bv = bias[col];
            int which = col >> 10;
            int c = col & 1023;
            int h = c >> 6, d = c & 63;
            int bh_ = (rowb >> 11) * NH + h;
            int tl = rowb & 2047;
            if (which == 2) {
                u16x4 vq;
#pragma unroll
                for (int i = 0; i < 4; ++i) vq[i] = f2b(acc[fm][fn][i] + bv);
                *(u16x4*)&v_out[(size_t)bh_ * (HD * T_SEQ) + (size_t)d * T_SEQ + tl] = vq;
            } else {
                unsigned short* dst = which ? k_out : q_out;
                float sc = which ? 1.0f : QSCALE;
#pragma unroll
                for (int i = 0; i < 4; ++i)
                    dst[((size_t)bh_ * T_SEQ + tl + i) * HD + d] =
                        f2b((acc[fm][fn][i] + bv) * sc);
            }
        }
    }
}

// ---------------- proj GEMM: proven 128^2 2-phase dbuf (round-6) ----------------
__global__ __launch_bounds__(256) void gemm_bt_kernel(
        const unsigned short* __restrict__ A, const unsigned short* __restrict__ Bt,
        const float* __restrict__ bias, float* __restrict__ outF, int M, int N, int K) {
    __shared__ alignas(16) unsigned short As[2][128 * 32];
    __shared__ alignas(16) unsigned short Bs[2][128 * 32];

    int tid = threadIdx.x;
    int wid = tid >> 6, lane = tid & 63;
    int g = lane >> 4, lc = lane & 15;
    int wr = (wid >> 1) * 64, wc = (wid & 1) * 64;
    int m0 = blockIdx.y * 128, n0 = blockIdx.x * 128;

    f32x4 acc[4][4];
#pragma unroll
    for (int m = 0; m < 4; ++m)
#pragma unroll
        for (int n = 0; n < 4; ++n) acc[m][n] = fzero4();

    const unsigned short* Ap = A + (size_t)(m0 + (tid >> 2)) * K + (tid & 3) * 8;
    const unsigned short* Bp = Bt + (size_t)(n0 + (tid >> 2)) * K + (tid & 3) * 8;
    int ldst = (wid * 16) * 32;
    int ldst2 = (64 + wid * 16) * 32;

#define GSTAGE(BUF, KOFF)                                      \
    gld16(Ap + (KOFF), &As[BUF][ldst]);                        \
    gld16(Ap + (size_t)64 * K + (KOFF), &As[BUF][ldst2]);      \
    gld16(Bp + (KOFF), &Bs[BUF][ldst]);                        \
    gld16(Bp + (size_t)64 * K + (KOFF), &Bs[BUF][ldst2]);

    GSTAGE(0, 0)
    __syncthreads();

    int nk = K >> 5;
    for (int it = 0; it < nk; ++it) {
        int cur = it & 1;
        if (it + 1 < nk) { GSTAGE(cur ^ 1, (it + 1) << 5) }

        bf16x8 af[4], bfr[4];
#pragma unroll
        for (int m = 0; m < 4; ++m)
            af[m] = *(const bf16x8*)&As[cur][(wr + m * 16 + lc) * 32 + g * 8];
#pragma unroll
        for (int n = 0; n < 4; ++n)
            bfr[n] = *(const bf16x8*)&Bs[cur][(wc + n * 16 + lc) * 32 + g * 8];
#pragma unroll
        for (int m = 0; m < 4; ++m)
#pragma unroll
            for (int n = 0; n < 4; ++n)
                acc[m][n] = mfma16(af[m], bfr[n], acc[m][n]);

        __syncthreads();
    }
#undef GSTAGE

#pragma unroll
    for (int m = 0; m < 4; ++m) {
        int rowb = m0 + wr + m * 16 + g * 4;
#pragma unroll
        for (int n = 0; n < 4; ++n) {
            int col = n0 + wc + n * 16 + lc;
            float bv = bias[col];
#pragma unroll
            for (int i = 0; i < 4; ++i)
                outF[(size_t)(rowb + i) * N + col] = acc[m][n][i] + bv;
        }
    }
}

// ---------------- flash attention: 32x32 MFMA, swapped QK^T ----------------
// 1024 blocks x 256 thr (4 waves). Block = (head, qg): q-tiles qg*4 + wid (32 rows each).
// S^T = mfma(K,Q): lane owns q = lane&31 -> lane-local softmax + defer-max.
// KV dbuf in LDS (16KB/tile, XOR-swizzled), prefetch next kt, one barrier per kt.
__global__ __launch_bounds__(256, 4) void attn32_kernel(
        const unsigned short* __restrict__ Qb, const unsigned short* __restrict__ Kb,
        const unsigned short* __restrict__ Vt, unsigned short* __restrict__ Yb) {
    __shared__ alignas(16) char smem[32768];  // 2 x (K 8KB + V 8KB)

    int tid = threadIdx.x;
    int wid = tid >> 6, lane = tid & 63;
    int ql = lane & 31, hi = lane >> 5;
    int ql7 = ql & 7;

    // balanced XCD-aware mapping: id -> (bh, qg)
    int id = blockIdx.x;
    int x = id & 7;          // XCD
    int k = id >> 3;         // 0..127 within XCD
    int r = k >> 5;          // dispatch round 0..3
    int c = k & 31;
    int hh = 2 * r + (c >> 4);
    int j = c & 15;
    int qg = (r & 1) ? (15 - j) : j;
    int bh = x * 8 + hh;
    size_t hb = (size_t)bh * (T_SEQ * HD);

    int qt = qg * 4 + wid;            // this wave's 32-row q-tile
    int q0 = qt * 32;
    int ktMax = qt >> 1;              // last (diagonal) KV tile for this wave
    int ntB = 2 * qg + 2;             // block's KV tile count (max over waves)

    // persistent Q B-frag (col=q=ql, elems d = dstep*16 + hi*8 + e)
    bf16x8 qf[4];
    const unsigned short* Qp = Qb + hb + (size_t)(q0 + ql) * HD + hi * 8;
#pragma unroll
    for (int d = 0; d < 4; ++d) qf[d] = *(const bf16x8*)(Qp + d * 16);

    f32x16 zz;
#pragma unroll
    for (int rr = 0; rr < 16; ++rr) zz[rr] = 0.f;
    f32x16 o0 = zz, o1 = zz;
    float mi = -__builtin_inff(), li = 0.f;

    // staging: wave w covers K rows [16w,16w+16) and V rows [16w,16w+16)
    int r8 = lane >> 3;
    int sslot8 = ((lane & 7) ^ r8) * 8;  // pre-swizzled source slot
    const unsigned short* Kg = Kb + hb + (size_t)(wid * 16 + r8) * HD + sslot8;
    const unsigned short* Vg = Vt + hb + (size_t)(wid * 16 + r8) * T_SEQ + sslot8;

    // prologue: stage kt=0 into buf 0
    gld16(Kg, smem + wid * 2048);
    gld16(Kg + 8 * HD, smem + wid * 2048 + 1024);
    gld16(Vg, smem + 8192 + wid * 2048);
    gld16(Vg + 8 * T_SEQ, smem + 8192 + wid * 2048 + 1024);
    __syncthreads();

#define KF(K0, D) (*(const bf16x8*)&KB_[(((K0)*32 + ql) << 6) + ((((D)*2 + hi) ^ ql7) << 3)])
#define VF(DB, T) (*(const bf16x8*)&VB_[(((DB)*32 + ql) << 6) + ((((T)*2 + hi) ^ ql7) << 3)])

    for (int kt = 0; kt < ntB; ++kt) {
        int cur = kt & 1;
        if (kt + 1 < ntB) {  // prefetch next tile into other buffer
            char* nb = smem + (cur ^ 1) * 16384;
            gld16(Kg + (size_t)(kt + 1) * 64 * HD, nb + wid * 2048);
            gld16(Kg + (size_t)((kt + 1) * 64 + 8) * HD, nb + wid * 2048 + 1024);
            gld16(Vg + (kt + 1) * 64, nb + 8192 + wid * 2048);
            gld16(Vg + (kt + 1) * 64 + 8 * T_SEQ, nb + 8192 + wid * 2048 + 1024);
        }
        if (kt <= ktMax) {
            const unsigned short* KB_ = (const unsigned short*)(smem + cur * 16384);
            const unsigned short* VB_ = (const unsigned short*)(smem + cur * 16384 + 8192);
            int k0 = kt * 64;

            f32x16 s0_, s1_;
            __builtin_amdgcn_s_setprio(1);
            s0_ = mfma32(KF(0, 0), qf[0], zz);
            s0_ = mfma32(KF(0, 1), qf[1], s0_);
            s0_ = mfma32(KF(0, 2), qf[2], s0_);
            s0_ = mfma32(KF(0, 3), qf[3], s0_);
            s1_ = mfma32(KF(1, 0), qf[0], zz);
            s1_ = mfma32(KF(1, 1), qf[1], s1_);
            s1_ = mfma32(KF(1, 2), qf[2], s1_);
            s1_ = mfma32(KF(1, 3), qf[3], s1_);
            __builtin_amdgcn_s_setprio(0);

            if (kt == ktMax) {  // causal mask, diagonal tile only
                int qg_ = q0 + ql;
#pragma unroll
                for (int rr = 0; rr < 16; ++rr) {
                    int kof_ = k0 + 8 * (rr >> 2) + (rr & 3) + 4 * hi;
                    if (kof_ > qg_) s0_[rr] = -__builtin_inff();
                    if (kof_ + 32 > qg_) s1_[rr] = -__builtin_inff();
                }
            }

            // lane-local row max (exp2 domain; q pre-scaled by 0.125*log2e)
            float t_[8];
#pragma unroll
            for (int rr = 0; rr < 8; ++rr)
                t_[rr] = fmaxf(fmaxf(s0_[rr], s0_[rr + 8]), fmaxf(s1_[rr], s1_[rr + 8]));
#pragma unroll
            for (int rr = 0; rr < 4; ++rr) t_[rr] = fmaxf(t_[rr], t_[rr + 4]);
            float pm_ = fmaxf(fmaxf(t_[0], t_[1]), fmaxf(t_[2], t_[3]));
            pm_ = fmaxf(pm_, __shfl_xor(pm_, 32));

            float mn_ = mi;
            if (!__all((int)(pm_ <= mi + 8.f))) {  // defer-max: skip rescale if small
                mn_ = fmaxf(mi, pm_);
                float f_ = __builtin_amdgcn_exp2f(mi - mn_);
                mi = mn_;
                li *= f_;
                o0 *= f_;
                o1 *= f_;
            }
#pragma unroll
            for (int rr = 0; rr < 16; ++rr) {
                s0_[rr] = __builtin_amdgcn_exp2f(s0_[rr] - mn_);
                s1_[rr] = __builtin_amdgcn_exp2f(s1_[rr] - mn_);
            }
            float u_[8];
#pragma unroll
            for (int rr = 0; rr < 8; ++rr)
                u_[rr] = (s0_[rr] + s0_[rr + 8]) + (s1_[rr] + s1_[rr + 8]);
#pragma unroll
            for (int rr = 0; rr < 4; ++rr) u_[rr] += u_[rr + 4];
            float ps_ = (u_[0] + u_[1]) + (u_[2] + u_[3]);
            ps_ += __shfl_xor(ps_, 32);
            li += ps_;

            // P -> PV B-frag via cvt_pk + permlane32_swap, then O += V^T P^T
#pragma unroll
            for (int K0_ = 0; K0_ < 2; ++K0_) {
#pragma unroll
                for (int h2_ = 0; h2_ < 2; ++h2_) {
                    float e0_ = K0_ ? s1_[8 * h2_ + 0] : s0_[8 * h2_ + 0];
                    float e1_ = K0_ ? s1_[8 * h2_ + 1] : s0_[8 * h2_ + 1];
                    float e2_ = K0_ ? s1_[8 * h2_ + 2] : s0_[8 * h2_ + 2];
                    float e3_ = K0_ ? s1_[8 * h2_ + 3] : s0_[8 * h2_ + 3];
                    float e4_ = K0_ ? s1_[8 * h2_ + 4] : s0_[8 * h2_ + 4];
                    float e5_ = K0_ ? s1_[8 * h2_ + 5] : s0_[8 * h2_ + 5];
                    float e6_ = K0_ ? s1_[8 * h2_ + 6] : s0_[8 * h2_ + 6];
                    float e7_ = K0_ ? s1_[8 * h2_ + 7] : s0_[8 * h2_ + 7];
                    unsigned a_, b_, c_, d_;
                    asm("v_cvt_pk_bf16_f32 %0, %1, %2" : "=v"(a_) : "v"(e0_), "v"(e1_));
                    asm("v_cvt_pk_bf16_f32 %0, %1, %2" : "=v"(b_) : "v"(e2_), "v"(e3_));
                    asm("v_cvt_pk_bf16_f32 %0, %1, %2" : "=v"(c_) : "v"(e4_), "v"(e5_));
                    asm("v_cvt_pk_bf16_f32 %0, %1, %2" : "=v"(d_) : "v"(e6_), "v"(e7_));
                    asm("v_permlane32_swap_b32 %0, %1" : "+v"(a_), "+v"(c_));
                    asm("v_permlane32_swap_b32 %0, %1" : "+v"(b_), "+v"(d_));
                    union { unsigned u[4]; bf16x8 v; } pf_;
                    pf_.u[0] = a_; pf_.u[1] = b_; pf_.u[2] = c_; pf_.u[3] = d_;
                    __builtin_amdgcn_s_setprio(1);
                    o0 = mfma32(VF(0, K0_ * 2 + h2_), pf_.v, o0);
                    o1 = mfma32(VF(1, K0_ * 2 + h2_), pf_.v, o1);
                    __builtin_amdgcn_s_setprio(0);
                }
            }
        }
        __syncthreads();
    }
#undef KF
#undef VF

    // epilogue: O^T[d][q]: q = q0+ql, d = dblk*32 + 8a + i + 4hi
    int bb = bh >> 4, h = bh & 15;
    float iv = 1.0f / li;
#pragma unroll
    for (int dblk = 0; dblk < 2; ++dblk) {
#pragma unroll
        for (int a = 0; a < 4; ++a) {
            u16x4 wv;
#pragma unroll
            for (int i = 0; i < 4; ++i)
                wv[i] = f2b((dblk ? o1[4 * a + i] : o0[4 * a + i]) * iv);
            int dq = dblk * 32 + 8 * a + 4 * hi;
            *(u16x4*)&Yb[((size_t)(bb * T_SEQ + q0 + ql)) * CDIM + h * HD + dq] = wv;
        }
    }
}

// ---------------- launch ----------------
extern "C" void kernel_launch(void* const* d_in, const int* in_sizes, int n_in,
                              void* d_out, int out_size, void* d_ws, size_t ws_size,
                              hipStream_t stream) {
    const float* x      = (const float*)d_in[0];
    const float* w_attn = (const float*)d_in[1];
    const float* b_attn = (const float*)d_in[2];
    const float* w_proj = (const float*)d_in[3];
    const float* b_proj = (const float*)d_in[4];
    float* out = (float*)d_out;

    // workspace layout (bytes):
    //   0         xb  : x bf16 [8192][1024]         16,777,216  (reused as yb)
    //   16777216  wTa : w_attn^T bf16 [3072][1024]   6,291,456
    //   23068672  wTp : w_proj^T bf16 [1024][1024]   2,097,152
    //   25165824  qb  : [64][2048][64] bf16         16,777,216  (pre-scaled by QSCALE)
    //   41943040  kb  : [64][2048][64] bf16         16,777,216
    //   58720256  vTb : [64][64][2048] bf16         16,777,216  (V^T, written by GEMM1)
    char* ws = (char*)d_ws;
    unsigned short* xb  = (unsigned short*)(ws);
    unsigned short* wTa = (unsigned short*)(ws + 16777216);
    unsigned short* wTp = (unsigned short*)(ws + 23068672);
    unsigned short* qb  = (unsigned short*)(ws + 25165824);
    unsigned short* kb  = (unsigned short*)(ws + 41943040);
    unsigned short* vTb = (unsigned short*)(ws + 58720256);
    unsigned short* yb  = xb;  // alias: xb dead after GEMM1

    cast_f32_bf16_kernel<<<2048, 256, 0, stream>>>(x, xb, (NB * T_SEQ * CDIM) / 8);
    transpose_cast_kernel<<<dim3(3072 / 32, 1024 / 32), dim3(32, 8), 0, stream>>>(
        w_attn, wTa, 1024, 3072);
    transpose_cast_kernel<<<dim3(1024 / 32, 1024 / 32), dim3(32, 8), 0, stream>>>(
        w_proj, wTp, 1024, 1024);

    // QKV GEMM: 256^2 tiles, grid 32x12 = 384 blocks (2 blocks/CU co-resident)
    gemm256_kernel<<<dim3(384), 512, 0, stream>>>(
        xb, wTa, b_attn, qb, kb, vTb, 8192, 3072, 1024, 12);

    // flash attention: 1024 balanced blocks x 4 waves
    attn32_kernel<<<dim3(1024), 256, 0, stream>>>(qb, kb, vTb, yb);

    // proj GEMM: proven 128^2 2-phase -> fp32 out
    gemm_bt_kernel<<<dim3(1024 / 128, 8192 / 128), 256, 0, stream>>>(
        yb, wTp, b_proj, out, 8192, 1024, 1024);
}

// Round 9
// 173.204 us; speedup vs baseline: 1.1455x; 1.0215x over previous
//
#include <hip/hip_runtime.h>

// CausalSelfAttention: B=4, T=2048, C=1024, H=16, hd=64
// cast->bf16, QKV+proj GEMM (128^2 2-phase dbuf + counted vmcnt(4), slot-swizzled LDS),
// 32x32-MFMA swapped-QK^T flash attention

#define T_SEQ 2048
#define NB 4
#define NH 16
#define CDIM 1024
#define HD 64
#define BH (NB * NH)
#define QSCALE 0.1803368801111204f  // 0.125 * log2(e)

typedef float f32x4 __attribute__((ext_vector_type(4)));
typedef float f32x16 __attribute__((ext_vector_type(16)));
typedef __bf16 bf16x8 __attribute__((ext_vector_type(8)));
typedef unsigned short u16x8 __attribute__((ext_vector_type(8)));
typedef unsigned short u16x4 __attribute__((ext_vector_type(4)));

__device__ __forceinline__ unsigned short f2b(float f) {
    union { float f; unsigned u; } v; v.f = f;
    unsigned u = v.u;
    u += 0x7FFFu + ((u >> 16) & 1u);   // round-to-nearest-even
    return (unsigned short)(u >> 16);
}

__device__ __forceinline__ f32x4 fzero4() {
    f32x4 z; z[0] = 0.f; z[1] = 0.f; z[2] = 0.f; z[3] = 0.f; return z;
}

__device__ __forceinline__ f32x4 mfma16(bf16x8 a, bf16x8 b, f32x4 c) {
    return __builtin_amdgcn_mfma_f32_16x16x32_bf16(a, b, c, 0, 0, 0);
}

__device__ __forceinline__ f32x16 mfma32(bf16x8 a, bf16x8 b, f32x16 c) {
    return __builtin_amdgcn_mfma_f32_32x32x16_bf16(a, b, c, 0, 0, 0);
}

// async global->LDS, 16B/lane; LDS dest = wave-uniform base + lane*16 (HW rule)
__device__ __forceinline__ void gld16(const void* gp, void* lp) {
    __builtin_amdgcn_global_load_lds(
        (const __attribute__((address_space(1))) unsigned int*)gp,
        (__attribute__((address_space(3))) unsigned int*)lp, 16, 0, 0);
}

#define FENCE asm volatile("" ::: "memory")

// ---------------- prep: fp32 -> bf16 cast ----------------
__global__ __launch_bounds__(256) void cast_f32_bf16_kernel(
        const float* __restrict__ in, unsigned short* __restrict__ out, int n8) {
    int i = blockIdx.x * 256 + threadIdx.x;
    int stride = gridDim.x * 256;
    for (; i < n8; i += stride) {
        const float4* p = reinterpret_cast<const float4*>(in) + (size_t)i * 2;
        float4 a = p[0], b = p[1];
        u16x8 o;
        o[0] = f2b(a.x); o[1] = f2b(a.y); o[2] = f2b(a.z); o[3] = f2b(a.w);
        o[4] = f2b(b.x); o[5] = f2b(b.y); o[6] = f2b(b.z); o[7] = f2b(b.w);
        *(reinterpret_cast<u16x8*>(out) + i) = o;
    }
}

// ---------------- prep: transpose + cast [R][C] f32 -> [C][R] bf16 ----------------
__global__ __launch_bounds__(256) void transpose_cast_kernel(
        const float* __restrict__ in, unsigned short* __restrict__ out, int R, int C) {
    __shared__ unsigned short tile[32][33];
    int tx = threadIdx.x, ty = threadIdx.y;
    int c0 = blockIdx.x * 32, r0 = blockIdx.y * 32;
    for (int rr = ty; rr < 32; rr += 8)
        tile[rr][tx] = f2b(in[(size_t)(r0 + rr) * C + c0 + tx]);
    __syncthreads();
    for (int rr = ty; rr < 32; rr += 8)
        out[(size_t)(c0 + rr) * R + r0 + tx] = tile[tx][rr];
}

// ---------------- GEMM: 128^2 2-phase dbuf + counted vmcnt ----------------
// C[M][N] = A[M][K] @ Bt[N][K]^T + bias. 256 thr, 4 waves (2x2 of 64x64).
// LDS [128][32] x2 per matrix; 16B-slot swizzle: phys slot = g ^ (row&3)
// (staged via gld16 with inverse-swizzled global source col).
// Per K-step: vmcnt(4) [prev tile ready, next tile in flight] -> s_barrier ->
// ds_read + 16 MFMA -> s_barrier -> stage(t+2) into the buffer just consumed.
// EPI=0: fp32 to outF. EPI=1: scatter q(*QSCALE)/k to [BH][T][HD], v to V^T [BH][HD][T].
template <int EPI>
__global__ __launch_bounds__(256) void gemm_bt_kernel(
        const unsigned short* __restrict__ A, const unsigned short* __restrict__ Bt,
        const float* __restrict__ bias, float* __restrict__ outF,
        unsigned short* __restrict__ q_out, unsigned short* __restrict__ k_out,
        unsigned short* __restrict__ v_out, int M, int N, int K) {
    __shared__ alignas(16) unsigned short As[2][128 * 32];
    __shared__ alignas(16) unsigned short Bs[2][128 * 32];

    int tid = threadIdx.x;
    int wid = tid >> 6, lane = tid & 63;
    int g = lane >> 4, lc = lane & 15;
    int wr = (wid >> 1) * 64, wc = (wid & 1) * 64;
    int m0 = blockIdx.y * 128, n0 = blockIdx.x * 128;

    f32x4 acc[4][4];
#pragma unroll
    for (int m = 0; m < 4; ++m)
#pragma unroll
        for (int n = 0; n < 4; ++n) acc[m][n] = fzero4();

    // staging: thread covers phys (row = tid>>2 [+64], slot = tid&3);
    // global source col pre-swizzled: ((tid&3) ^ (row&3)) * 8  (row&3 == (tid>>2)&3)
    int srow = tid >> 2;
    int scol = ((tid & 3) ^ (srow & 3)) * 8;
    const unsigned short* Ap = A + (size_t)(m0 + srow) * K + scol;
    const unsigned short* Bp = Bt + (size_t)(n0 + srow) * K + scol;
    int ldst = (wid * 16) * 32;
    int ldst2 = (64 + wid * 16) * 32;

#define GSTAGE(BUF, KOFF)                                      \
    gld16(Ap + (KOFF), &As[BUF][ldst]);                        \
    gld16(Ap + (size_t)64 * K + (KOFF), &As[BUF][ldst2]);      \
    gld16(Bp + (KOFF), &Bs[BUF][ldst]);                        \
    gld16(Bp + (size_t)64 * K + (KOFF), &Bs[BUF][ldst2]);

    GSTAGE(0, 0)
    GSTAGE(1, 32)

    // read slot swizzle: phys slot = g ^ (row&3), row&3 == lc&3 for our rows
    int swz8 = (g ^ (lc & 3)) * 8;

    int nk = K >> 5;
    for (int it = 0; it < nk; ++it) {
        int cur = it & 1;
        if (it + 1 < nk) { asm volatile("s_waitcnt vmcnt(4)" ::: "memory"); }
        else             { asm volatile("s_waitcnt vmcnt(0)" ::: "memory"); }
        FENCE; __builtin_amdgcn_s_barrier(); FENCE;  // tile `it` visible to all

        bf16x8 af[4], bfr[4];
#pragma unroll
        for (int m = 0; m < 4; ++m)
            af[m] = *(const bf16x8*)&As[cur][(wr + m * 16 + lc) * 32 + swz8];
#pragma unroll
        for (int n = 0; n < 4; ++n)
            bfr[n] = *(const bf16x8*)&Bs[cur][(wc + n * 16 + lc) * 32 + swz8];

        __builtin_amdgcn_s_setprio(1);
#pragma unroll
        for (int m = 0; m < 4; ++m)
#pragma unroll
            for (int n = 0; n < 4; ++n)
                acc[m][n] = mfma16(af[m], bfr[n], acc[m][n]);
        __builtin_amdgcn_s_setprio(0);

        FENCE; __builtin_amdgcn_s_barrier(); FENCE;  // all reads of `cur` consumed
        if (it + 2 < nk) { GSTAGE(cur, (it + 2) << 5) }
    }
#undef GSTAGE

#pragma unroll
    for (int m = 0; m < 4; ++m) {
        int rowb = m0 + wr + m * 16 + g * 4;
#pragma unroll
        for (int n = 0; n < 4; ++n) {
            int col = n0 + wc + n * 16 + lc;
            float bv = bias[col];
            if (EPI == 0) {
#pragma unroll
                for (int i = 0; i < 4; ++i)
                    outF[(size_t)(rowb + i) * N + col] = acc[m][n][i] + bv;
            } else {
                int which = col >> 10;
                int c = col & 1023;
                int h = c >> 6, d = c & 63;
                int bh_ = (rowb >> 11) * NH + h;
                int tl = rowb & 2047;
                if (which == 2) {
                    u16x4 vq;
#pragma unroll
                    for (int i = 0; i < 4; ++i) vq[i] = f2b(acc[m][n][i] + bv);
                    *(u16x4*)&v_out[(size_t)bh_ * (HD * T_SEQ) + (size_t)d * T_SEQ + tl] = vq;
                } else {
                    unsigned short* dst = which ? k_out : q_out;
                    float sc = which ? 1.0f : QSCALE;
#pragma unroll
                    for (int i = 0; i < 4; ++i)
                        dst[((size_t)bh_ * T_SEQ + tl + i) * HD + d] =
                            f2b((acc[m][n][i] + bv) * sc);
                }
            }
        }
    }
}

// ---------------- flash attention: 32x32 MFMA, swapped QK^T ----------------
// 1024 blocks x 256 thr (4 waves). Block = (head, qg): q-tiles qg*4 + wid (32 rows each).
// S^T = mfma(K,Q): lane owns q = lane&31 -> lane-local softmax + defer-max.
// KV dbuf in LDS (16KB/tile, XOR-swizzled), prefetch next kt, one barrier per kt.
__global__ __launch_bounds__(256, 4) void attn32_kernel(
        const unsigned short* __restrict__ Qb, const unsigned short* __restrict__ Kb,
        const unsigned short* __restrict__ Vt, unsigned short* __restrict__ Yb) {
    __shared__ alignas(16) char smem[32768];  // 2 x (K 8KB + V 8KB)

    int tid = threadIdx.x;
    int wid = tid >> 6, lane = tid & 63;
    int ql = lane & 31, hi = lane >> 5;
    int ql7 = ql & 7;

    // balanced XCD-aware mapping: id -> (bh, qg)
    int id = blockIdx.x;
    int x = id & 7;          // XCD
    int k = id >> 3;         // 0..127 within XCD
    int r = k >> 5;          // dispatch round 0..3
    int c = k & 31;
    int hh = 2 * r + (c >> 4);
    int j = c & 15;
    int qg = (r & 1) ? (15 - j) : j;
    int bh = x * 8 + hh;
    size_t hb = (size_t)bh * (T_SEQ * HD);

    int qt = qg * 4 + wid;            // this wave's 32-row q-tile
    int q0 = qt * 32;
    int ktMax = qt >> 1;              // last (diagonal) KV tile for this wave
    int ntB = 2 * qg + 2;             // block's KV tile count (max over waves)

    // persistent Q B-frag (col=q=ql, elems d = dstep*16 + hi*8 + e)
    bf16x8 qf[4];
    const unsigned short* Qp = Qb + hb + (size_t)(q0 + ql) * HD + hi * 8;
#pragma unroll
    for (int d = 0; d < 4; ++d) qf[d] = *(const bf16x8*)(Qp + d * 16);

    f32x16 zz;
#pragma unroll
    for (int rr = 0; rr < 16; ++rr) zz[rr] = 0.f;
    f32x16 o0 = zz, o1 = zz;
    float mi = -__builtin_inff(), li = 0.f;

    // staging: wave w covers K rows [16w,16w+16) and V rows [16w,16w+16)
    int r8 = lane >> 3;
    int sslot8 = ((lane & 7) ^ r8) * 8;  // pre-swizzled source slot
    const unsigned short* Kg = Kb + hb + (size_t)(wid * 16 + r8) * HD + sslot8;
    const unsigned short* Vg = Vt + hb + (size_t)(wid * 16 + r8) * T_SEQ + sslot8;

    // prologue: stage kt=0 into buf 0
    gld16(Kg, smem + wid * 2048);
    gld16(Kg + 8 * HD, smem + wid * 2048 + 1024);
    gld16(Vg, smem + 8192 + wid * 2048);
    gld16(Vg + 8 * T_SEQ, smem + 8192 + wid * 2048 + 1024);
    __syncthreads();

#define KF(K0, D) (*(const bf16x8*)&KB_[(((K0)*32 + ql) << 6) + ((((D)*2 + hi) ^ ql7) << 3)])
#define VF(DB, T) (*(const bf16x8*)&VB_[(((DB)*32 + ql) << 6) + ((((T)*2 + hi) ^ ql7) << 3)])

    for (int kt = 0; kt < ntB; ++kt) {
        int cur = kt & 1;
        if (kt + 1 < ntB) {  // prefetch next tile into other buffer
            char* nb = smem + (cur ^ 1) * 16384;
            gld16(Kg + (size_t)(kt + 1) * 64 * HD, nb + wid * 2048);
            gld16(Kg + (size_t)((kt + 1) * 64 + 8) * HD, nb + wid * 2048 + 1024);
            gld16(Vg + (kt + 1) * 64, nb + 8192 + wid * 2048);
            gld16(Vg + (kt + 1) * 64 + 8 * T_SEQ, nb + 8192 + wid * 2048 + 1024);
        }
        if (kt <= ktMax) {
            const unsigned short* KB_ = (const unsigned short*)(smem + cur * 16384);
            const unsigned short* VB_ = (const unsigned short*)(smem + cur * 16384 + 8192);
            int k0 = kt * 64;

            f32x16 s0_, s1_;
            __builtin_amdgcn_s_setprio(1);
            s0_ = mfma32(KF(0, 0), qf[0], zz);
            s0_ = mfma32(KF(0, 1), qf[1], s0_);
            s0_ = mfma32(KF(0, 2), qf[2], s0_);
            s0_ = mfma32(KF(0, 3), qf[3], s0_);
            s1_ = mfma32(KF(1, 0), qf[0], zz);
            s1_ = mfma32(KF(1, 1), qf[1], s1_);
            s1_ = mfma32(KF(1, 2), qf[2], s1_);
            s1_ = mfma32(KF(1, 3), qf[3], s1_);
            __builtin_amdgcn_s_setprio(0);

            if (kt == ktMax) {  // causal mask, diagonal tile only
                int qg_ = q0 + ql;
#pragma unroll
                for (int rr = 0; rr < 16; ++rr) {
                    int kof_ = k0 + 8 * (rr >> 2) + (rr & 3) + 4 * hi;
                    if (kof_ > qg_) s0_[rr] = -__builtin_inff();
                    if (kof_ + 32 > qg_) s1_[rr] = -__builtin_inff();
                }
            }

            // lane-local row max (exp2 domain; q pre-scaled by 0.125*log2e)
            float t_[8];
#pragma unroll
            for (int rr = 0; rr < 8; ++rr)
                t_[rr] = fmaxf(fmaxf(s0_[rr], s0_[rr + 8]), fmaxf(s1_[rr], s1_[rr + 8]));
#pragma unroll
            for (int rr = 0; rr < 4; ++rr) t_[rr] = fmaxf(t_[rr], t_[rr + 4]);
            float pm_ = fmaxf(fmaxf(t_[0], t_[1]), fmaxf(t_[2], t_[3]));
            pm_ = fmaxf(pm_, __shfl_xor(pm_, 32));

            float mn_ = mi;
            if (!__all((int)(pm_ <= mi + 8.f))) {  // defer-max: skip rescale if small
                mn_ = fmaxf(mi, pm_);
                float f_ = __builtin_amdgcn_exp2f(mi - mn_);
                mi = mn_;
                li *= f_;
                o0 *= f_;
                o1 *= f_;
            }
#pragma unroll
            for (int rr = 0; rr < 16; ++rr) {
                s0_[rr] = __builtin_amdgcn_exp2f(s0_[rr] - mn_);
                s1_[rr] = __builtin_amdgcn_exp2f(s1_[rr] - mn_);
            }
            float u_[8];
#pragma unroll
            for (int rr = 0; rr < 8; ++rr)
                u_[rr] = (s0_[rr] + s0_[rr + 8]) + (s1_[rr] + s1_[rr + 8]);
#pragma unroll
            for (int rr = 0; rr < 4; ++rr) u_[rr] += u_[rr + 4];
            float ps_ = (u_[0] + u_[1]) + (u_[2] + u_[3]);
            ps_ += __shfl_xor(ps_, 32);
            li += ps_;

            // P -> PV B-frag via cvt_pk + permlane32_swap, then O += V^T P^T
#pragma unroll
            for (int K0_ = 0; K0_ < 2; ++K0_) {
#pragma unroll
                for (int h2_ = 0; h2_ < 2; ++h2_) {
                    float e0_ = K0_ ? s1_[8 * h2_ + 0] : s0_[8 * h2_ + 0];
                    float e1_ = K0_ ? s1_[8 * h2_ + 1] : s0_[8 * h2_ + 1];
                    float e2_ = K0_ ? s1_[8 * h2_ + 2] : s0_[8 * h2_ + 2];
                    float e3_ = K0_ ? s1_[8 * h2_ + 3] : s0_[8 * h2_ + 3];
                    float e4_ = K0_ ? s1_[8 * h2_ + 4] : s0_[8 * h2_ + 4];
                    float e5_ = K0_ ? s1_[8 * h2_ + 5] : s0_[8 * h2_ + 5];
                    float e6_ = K0_ ? s1_[8 * h2_ + 6] : s0_[8 * h2_ + 6];
                    float e7_ = K0_ ? s1_[8 * h2_ + 7] : s0_[8 * h2_ + 7];
                    unsigned a_, b_, c_, d_;
                    asm("v_cvt_pk_bf16_f32 %0, %1, %2" : "=v"(a_) : "v"(e0_), "v"(e1_));
                    asm("v_cvt_pk_bf16_f32 %0, %1, %2" : "=v"(b_) : "v"(e2_), "v"(e3_));
                    asm("v_cvt_pk_bf16_f32 %0, %1, %2" : "=v"(c_) : "v"(e4_), "v"(e5_));
                    asm("v_cvt_pk_bf16_f32 %0, %1, %2" : "=v"(d_) : "v"(e6_), "v"(e7_));
                    asm("v_permlane32_swap_b32 %0, %1" : "+v"(a_), "+v"(c_));
                    asm("v_permlane32_swap_b32 %0, %1" : "+v"(b_), "+v"(d_));
                    union { unsigned u[4]; bf16x8 v; } pf_;
                    pf_.u[0] = a_; pf_.u[1] = b_; pf_.u[2] = c_; pf_.u[3] = d_;
                    __builtin_amdgcn_s_setprio(1);
                    o0 = mfma32(VF(0, K0_ * 2 + h2_), pf_.v, o0);
                    o1 = mfma32(VF(1, K0_ * 2 + h2_), pf_.v, o1);
                    __builtin_amdgcn_s_setprio(0);
                }
            }
        }
        __syncthreads();
    }
#undef KF
#undef VF

    // epilogue: O^T[d][q]: q = q0+ql, d = dblk*32 + 8a + i + 4hi
    int bb = bh >> 4, h = bh & 15;
    float iv = 1.0f / li;
#pragma unroll
    for (int dblk = 0; dblk < 2; ++dblk) {
#pragma unroll
        for (int a = 0; a < 4; ++a) {
            u16x4 wv;
#pragma unroll
            for (int i = 0; i < 4; ++i)
                wv[i] = f2b((dblk ? o1[4 * a + i] : o0[4 * a + i]) * iv);
            int dq = dblk * 32 + 8 * a + 4 * hi;
            *(u16x4*)&Yb[((size_t)(bb * T_SEQ + q0 + ql)) * CDIM + h * HD + dq] = wv;
        }
    }
}

// ---------------- launch ----------------
extern "C" void kernel_launch(void* const* d_in, const int* in_sizes, int n_in,
                              void* d_out, int out_size, void* d_ws, size_t ws_size,
                              hipStream_t stream) {
    const float* x      = (const float*)d_in[0];
    const float* w_attn = (const float*)d_in[1];
    const float* b_attn = (const float*)d_in[2];
    const float* w_proj = (const float*)d_in[3];
    const float* b_proj = (const float*)d_in[4];
    float* out = (float*)d_out;

    // workspace layout (bytes):
    //   0         xb  : x bf16 [8192][1024]         16,777,216  (reused as yb)
    //   16777216  wTa : w_attn^T bf16 [3072][1024]   6,291,456
    //   23068672  wTp : w_proj^T bf16 [1024][1024]   2,097,152
    //   25165824  qb  : [64][2048][64] bf16         16,777,216  (pre-scaled by QSCALE)
    //   41943040  kb  : [64][2048][64] bf16         16,777,216
    //   58720256  vTb : [64][64][2048] bf16         16,777,216  (V^T, written by GEMM1)
    char* ws = (char*)d_ws;
    unsigned short* xb  = (unsigned short*)(ws);
    unsigned short* wTa = (unsigned short*)(ws + 16777216);
    unsigned short* wTp = (unsigned short*)(ws + 23068672);
    unsigned short* qb  = (unsigned short*)(ws + 25165824);
    unsigned short* kb  = (unsigned short*)(ws + 41943040);
    unsigned short* vTb = (unsigned short*)(ws + 58720256);
    unsigned short* yb  = xb;  // alias: xb dead after GEMM1

    cast_f32_bf16_kernel<<<2048, 256, 0, stream>>>(x, xb, (NB * T_SEQ * CDIM) / 8);
    transpose_cast_kernel<<<dim3(3072 / 32, 1024 / 32), dim3(32, 8), 0, stream>>>(
        w_attn, wTa, 1024, 3072);
    transpose_cast_kernel<<<dim3(1024 / 32, 1024 / 32), dim3(32, 8), 0, stream>>>(
        w_proj, wTp, 1024, 1024);

    // QKV GEMM: q (scaled), k row-major; v written transposed per head
    gemm_bt_kernel<1><<<dim3(3072 / 128, 8192 / 128), 256, 0, stream>>>(
        xb, wTa, b_attn, nullptr, qb, kb, vTb, 8192, 3072, 1024);

    // flash attention: 1024 balanced blocks x 4 waves
    attn32_kernel<<<dim3(1024), 256, 0, stream>>>(qb, kb, vTb, yb);

    // proj GEMM -> fp32 out
    gemm_bt_kernel<0><<<dim3(1024 / 128, 8192 / 128), 256, 0, stream>>>(
        yb, wTp, b_proj, out, nullptr, nullptr, nullptr, 8192, 1024, 1024);
}

// Round 10
// 168.788 us; speedup vs baseline: 1.1755x; 1.0262x over previous
//
#include <hip/hip_runtime.h>

// CausalSelfAttention: B=4, T=2048, C=1024, H=16, hd=64
// fused prep, QKV GEMM (128^2, A-single/B-dbuf 24KB = 6 blocks/CU, counted vmcnt),
// 32x32-MFMA swapped-QK^T flash attention (counted-vmcnt barriers), proj GEMM

#define T_SEQ 2048
#define NB 4
#define NH 16
#define CDIM 1024
#define HD 64
#define BH (NB * NH)
#define QSCALE 0.1803368801111204f  // 0.125 * log2(e)

typedef float f32x4 __attribute__((ext_vector_type(4)));
typedef float f32x16 __attribute__((ext_vector_type(16)));
typedef __bf16 bf16x8 __attribute__((ext_vector_type(8)));
typedef unsigned short u16x8 __attribute__((ext_vector_type(8)));
typedef unsigned short u16x4 __attribute__((ext_vector_type(4)));

__device__ __forceinline__ unsigned short f2b(float f) {
    union { float f; unsigned u; } v; v.f = f;
    unsigned u = v.u;
    u += 0x7FFFu + ((u >> 16) & 1u);   // round-to-nearest-even
    return (unsigned short)(u >> 16);
}

__device__ __forceinline__ f32x4 fzero4() {
    f32x4 z; z[0] = 0.f; z[1] = 0.f; z[2] = 0.f; z[3] = 0.f; return z;
}

__device__ __forceinline__ f32x4 mfma16(bf16x8 a, bf16x8 b, f32x4 c) {
    return __builtin_amdgcn_mfma_f32_16x16x32_bf16(a, b, c, 0, 0, 0);
}

__device__ __forceinline__ f32x16 mfma32(bf16x8 a, bf16x8 b, f32x16 c) {
    return __builtin_amdgcn_mfma_f32_32x32x16_bf16(a, b, c, 0, 0, 0);
}

// async global->LDS, 16B/lane; LDS dest = wave-uniform base + lane*16 (HW rule)
__device__ __forceinline__ void gld16(const void* gp, void* lp) {
    __builtin_amdgcn_global_load_lds(
        (const __attribute__((address_space(1))) unsigned int*)gp,
        (__attribute__((address_space(3))) unsigned int*)lp, 16, 0, 0);
}

#define FENCE asm volatile("" ::: "memory")

// ---------------- fused prep: cast x, transpose w_attn, transpose w_proj ----------------
__device__ __forceinline__ void transpose_tile(
        const float* __restrict__ in, unsigned short* __restrict__ out,
        int R, int C, int bx, int by) {
    __shared__ unsigned short tile[32][33];
    int tx = threadIdx.x & 31, ty = threadIdx.x >> 5;
    int c0 = bx * 32, r0 = by * 32;
#pragma unroll
    for (int rr = ty; rr < 32; rr += 8)
        tile[rr][tx] = f2b(in[(size_t)(r0 + rr) * C + c0 + tx]);
    __syncthreads();
#pragma unroll
    for (int rr = ty; rr < 32; rr += 8)
        out[(size_t)(c0 + rr) * R + r0 + tx] = tile[tx][rr];
}

__global__ __launch_bounds__(256) void prep_kernel(
        const float* __restrict__ x, const float* __restrict__ wa,
        const float* __restrict__ wp, unsigned short* __restrict__ xb,
        unsigned short* __restrict__ wTa, unsigned short* __restrict__ wTp) {
    int b = blockIdx.x;
    if (b < 1024) {
        // cast x -> bf16: 1,048,576 groups of 8, 1024 blocks x 256 x 4
        int n8 = (NB * T_SEQ * CDIM) / 8;
        for (int i = b * 256 + threadIdx.x; i < n8; i += 1024 * 256) {
            const float4* p = reinterpret_cast<const float4*>(x) + (size_t)i * 2;
            float4 a = p[0], c = p[1];
            u16x8 o;
            o[0] = f2b(a.x); o[1] = f2b(a.y); o[2] = f2b(a.z); o[3] = f2b(a.w);
            o[4] = f2b(c.x); o[5] = f2b(c.y); o[6] = f2b(c.z); o[7] = f2b(c.w);
            *(reinterpret_cast<u16x8*>(xb) + i) = o;
        }
    } else if (b < 1024 + 3072) {
        int t = b - 1024;   // w_attn [1024][3072]: 96 x 32 tiles
        transpose_tile(wa, wTa, 1024, 3072, t % 96, t / 96);
    } else {
        int t = b - 4096;   // w_proj [1024][1024]: 32 x 32 tiles
        transpose_tile(wp, wTp, 1024, 1024, t % 32, t / 32);
    }
}

// ---------------- QKV GEMM: 128^2, A-single + B-dbuf (24KB -> 6 blocks/CU) ----------------
// C[M][N] = A[M][K] @ Bt[N][K]^T + bias; scatter q(*QSCALE)/k to [BH][T][HD], v to V^T.
// Per K-step: vmcnt(2) [A(t),B(t) done; B(t+1) in flight] -> s_barrier ->
// ds_read + 16 MFMA -> lgkmcnt(0) -> s_barrier -> stage A(t+1), B(t+2).
__global__ __launch_bounds__(256) void gemm_qkv_kernel(
        const unsigned short* __restrict__ A, const unsigned short* __restrict__ Bt,
        const float* __restrict__ bias,
        unsigned short* __restrict__ q_out, unsigned short* __restrict__ k_out,
        unsigned short* __restrict__ v_out, int M, int N, int K) {
    __shared__ alignas(16) unsigned short As[128 * 32];     // 8KB single
    __shared__ alignas(16) unsigned short Bs[2][128 * 32];  // 16KB dbuf

    int tid = threadIdx.x;
    int wid = tid >> 6, lane = tid & 63;
    int g = lane >> 4, lc = lane & 15;
    int wr = (wid >> 1) * 64, wc = (wid & 1) * 64;
    int m0 = blockIdx.y * 128, n0 = blockIdx.x * 128;

    f32x4 acc[4][4];
#pragma unroll
    for (int m = 0; m < 4; ++m)
#pragma unroll
        for (int n = 0; n < 4; ++n) acc[m][n] = fzero4();

    int srow = tid >> 2;
    int scol = ((tid & 3) ^ (srow & 3)) * 8;  // inverse-swizzled source col
    const unsigned short* Ap = A + (size_t)(m0 + srow) * K + scol;
    const unsigned short* Bp = Bt + (size_t)(n0 + srow) * K + scol;
    int ldst = (wid * 16) * 32;
    int ldst2 = (64 + wid * 16) * 32;

#define STAGE_A(KOFF) {                                    \
        gld16(Ap + (KOFF), &As[ldst]);                     \
        gld16(Ap + (size_t)64 * K + (KOFF), &As[ldst2]); }
#define STAGE_B(BUF, KOFF) {                                       \
        gld16(Bp + (KOFF), &Bs[BUF][ldst]);                        \
        gld16(Bp + (size_t)64 * K + (KOFF), &Bs[BUF][ldst2]); }

    STAGE_B(0, 0)    // B(0)
    STAGE_A(0)       // A(0)
    STAGE_B(1, 32)   // B(1)

    int swz8 = (g ^ (lc & 3)) * 8;  // read slot swizzle (row&3 == lc&3)

    int nk = K >> 5;
    for (int it = 0; it < nk; ++it) {
        if (it + 1 < nk) { asm volatile("s_waitcnt vmcnt(2)" ::: "memory"); }
        else             { asm volatile("s_waitcnt vmcnt(0)" ::: "memory"); }
        FENCE; __builtin_amdgcn_s_barrier(); FENCE;  // A(it), B(it) visible

        bf16x8 af[4], bfr[4];
        const unsigned short* Bb = Bs[it & 1];
#pragma unroll
        for (int m = 0; m < 4; ++m)
            af[m] = *(const bf16x8*)&As[(wr + m * 16 + lc) * 32 + swz8];
#pragma unroll
        for (int n = 0; n < 4; ++n)
            bfr[n] = *(const bf16x8*)&Bb[(wc + n * 16 + lc) * 32 + swz8];

        __builtin_amdgcn_s_setprio(1);
#pragma unroll
        for (int m = 0; m < 4; ++m)
#pragma unroll
            for (int n = 0; n < 4; ++n)
                acc[m][n] = mfma16(af[m], bfr[n], acc[m][n]);
        __builtin_amdgcn_s_setprio(0);

        asm volatile("s_waitcnt lgkmcnt(0)" ::: "memory");
        FENCE; __builtin_amdgcn_s_barrier(); FENCE;  // all reads consumed
        if (it + 1 < nk) STAGE_A((it + 1) << 5)
        if (it + 2 < nk) STAGE_B(it & 1, (it + 2) << 5)
    }
#undef STAGE_A
#undef STAGE_B

    // epilogue: scatter q (scaled), k row-major; v transposed per head
#pragma unroll
    for (int m = 0; m < 4; ++m) {
        int rowb = m0 + wr + m * 16 + g * 4;
#pragma unroll
        for (int n = 0; n < 4; ++n) {
            int col = n0 + wc + n * 16 + lc;
            float bv = bias[col];
            int which = col >> 10;
            int c = col & 1023;
            int h = c >> 6, d = c & 63;
            int bh_ = (rowb >> 11) * NH + h;
            int tl = rowb & 2047;
            if (which == 2) {
                u16x4 vq;
#pragma unroll
                for (int i = 0; i < 4; ++i) vq[i] = f2b(acc[m][n][i] + bv);
                *(u16x4*)&v_out[(size_t)bh_ * (HD * T_SEQ) + (size_t)d * T_SEQ + tl] = vq;
            } else {
                unsigned short* dst = which ? k_out : q_out;
                float sc = which ? 1.0f : QSCALE;
#pragma unroll
                for (int i = 0; i < 4; ++i)
                    dst[((size_t)bh_ * T_SEQ + tl + i) * HD + d] =
                        f2b((acc[m][n][i] + bv) * sc);
            }
        }
    }
}

// ---------------- proj GEMM: 128^2 2-phase dbuf + counted vmcnt (round-9) ----------------
__global__ __launch_bounds__(256) void gemm_proj_kernel(
        const unsigned short* __restrict__ A, const unsigned short* __restrict__ Bt,
        const float* __restrict__ bias, float* __restrict__ outF, int M, int N, int K) {
    __shared__ alignas(16) unsigned short As[2][128 * 32];
    __shared__ alignas(16) unsigned short Bs[2][128 * 32];

    int tid = threadIdx.x;
    int wid = tid >> 6, lane = tid & 63;
    int g = lane >> 4, lc = lane & 15;
    int wr = (wid >> 1) * 64, wc = (wid & 1) * 64;
    int m0 = blockIdx.y * 128, n0 = blockIdx.x * 128;

    f32x4 acc[4][4];
#pragma unroll
    for (int m = 0; m < 4; ++m)
#pragma unroll
        for (int n = 0; n < 4; ++n) acc[m][n] = fzero4();

    int srow = tid >> 2;
    int scol = ((tid & 3) ^ (srow & 3)) * 8;
    const unsigned short* Ap = A + (size_t)(m0 + srow) * K + scol;
    const unsigned short* Bp = Bt + (size_t)(n0 + srow) * K + scol;
    int ldst = (wid * 16) * 32;
    int ldst2 = (64 + wid * 16) * 32;

#define GSTAGE(BUF, KOFF)                                      \
    gld16(Ap + (KOFF), &As[BUF][ldst]);                        \
    gld16(Ap + (size_t)64 * K + (KOFF), &As[BUF][ldst2]);      \
    gld16(Bp + (KOFF), &Bs[BUF][ldst]);                        \
    gld16(Bp + (size_t)64 * K + (KOFF), &Bs[BUF][ldst2]);

    GSTAGE(0, 0)
    GSTAGE(1, 32)

    int swz8 = (g ^ (lc & 3)) * 8;

    int nk = K >> 5;
    for (int it = 0; it < nk; ++it) {
        int cur = it & 1;
        if (it + 1 < nk) { asm volatile("s_waitcnt vmcnt(4)" ::: "memory"); }
        else             { asm volatile("s_waitcnt vmcnt(0)" ::: "memory"); }
        FENCE; __builtin_amdgcn_s_barrier(); FENCE;

        bf16x8 af[4], bfr[4];
#pragma unroll
        for (int m = 0; m < 4; ++m)
            af[m] = *(const bf16x8*)&As[cur][(wr + m * 16 + lc) * 32 + swz8];
#pragma unroll
        for (int n = 0; n < 4; ++n)
            bfr[n] = *(const bf16x8*)&Bs[cur][(wc + n * 16 + lc) * 32 + swz8];

        __builtin_amdgcn_s_setprio(1);
#pragma unroll
        for (int m = 0; m < 4; ++m)
#pragma unroll
            for (int n = 0; n < 4; ++n)
                acc[m][n] = mfma16(af[m], bfr[n], acc[m][n]);
        __builtin_amdgcn_s_setprio(0);

        FENCE; __builtin_amdgcn_s_barrier(); FENCE;
        if (it + 2 < nk) { GSTAGE(cur, (it + 2) << 5) }
    }
#undef GSTAGE

#pragma unroll
    for (int m = 0; m < 4; ++m) {
        int rowb = m0 + wr + m * 16 + g * 4;
#pragma unroll
        for (int n = 0; n < 4; ++n) {
            int col = n0 + wc + n * 16 + lc;
            float bv = bias[col];
#pragma unroll
            for (int i = 0; i < 4; ++i)
                outF[(size_t)(rowb + i) * N + col] = acc[m][n][i] + bv;
        }
    }
}

// ---------------- flash attention: 32x32 MFMA, swapped QK^T, counted-vmcnt sync ----------
__global__ __launch_bounds__(256, 4) void attn32_kernel(
        const unsigned short* __restrict__ Qb, const unsigned short* __restrict__ Kb,
        const unsigned short* __restrict__ Vt, unsigned short* __restrict__ Yb) {
    __shared__ alignas(16) char smem[32768];  // 2 x (K 8KB + V 8KB)

    int tid = threadIdx.x;
    int wid = tid >> 6, lane = tid & 63;
    int ql = lane & 31, hi = lane >> 5;
    int ql7 = ql & 7;

    // balanced XCD-aware mapping: id -> (bh, qg)
    int id = blockIdx.x;
    int x = id & 7;
    int k = id >> 3;
    int r = k >> 5;
    int c = k & 31;
    int hh = 2 * r + (c >> 4);
    int j = c & 15;
    int qg = (r & 1) ? (15 - j) : j;
    int bh = x * 8 + hh;
    size_t hb = (size_t)bh * (T_SEQ * HD);

    int qt = qg * 4 + wid;
    int q0 = qt * 32;
    int ktMax = qt >> 1;
    int ntB = 2 * qg + 2;

    bf16x8 qf[4];
    const unsigned short* Qp = Qb + hb + (size_t)(q0 + ql) * HD + hi * 8;
#pragma unroll
    for (int d = 0; d < 4; ++d) qf[d] = *(const bf16x8*)(Qp + d * 16);

    f32x16 zz;
#pragma unroll
    for (int rr = 0; rr < 16; ++rr) zz[rr] = 0.f;
    f32x16 o0 = zz, o1 = zz;
    float mi = -__builtin_inff(), li = 0.f;

    int r8 = lane >> 3;
    int sslot8 = ((lane & 7) ^ r8) * 8;
    const unsigned short* Kg = Kb + hb + (size_t)(wid * 16 + r8) * HD + sslot8;
    const unsigned short* Vg = Vt + hb + (size_t)(wid * 16 + r8) * T_SEQ + sslot8;

    // prologue: stage kt=0 into buf 0
    gld16(Kg, smem + wid * 2048);
    gld16(Kg + 8 * HD, smem + wid * 2048 + 1024);
    gld16(Vg, smem + 8192 + wid * 2048);
    gld16(Vg + 8 * T_SEQ, smem + 8192 + wid * 2048 + 1024);
    __syncthreads();

#define KF(K0, D) (*(const bf16x8*)&KB_[(((K0)*32 + ql) << 6) + ((((D)*2 + hi) ^ ql7) << 3)])
#define VF(DB, T) (*(const bf16x8*)&VB_[(((DB)*32 + ql) << 6) + ((((T)*2 + hi) ^ ql7) << 3)])

    for (int kt = 0; kt < ntB; ++kt) {
        int cur = kt & 1;
        bool pf = (kt + 1 < ntB);
        if (pf) {  // prefetch next tile into other buffer
            char* nb = smem + (cur ^ 1) * 16384;
            gld16(Kg + (size_t)(kt + 1) * 64 * HD, nb + wid * 2048);
            gld16(Kg + (size_t)((kt + 1) * 64 + 8) * HD, nb + wid * 2048 + 1024);
            gld16(Vg + (kt + 1) * 64, nb + 8192 + wid * 2048);
            gld16(Vg + (kt + 1) * 64 + 8 * T_SEQ, nb + 8192 + wid * 2048 + 1024);
        }
        // wait only the PREVIOUS iter's 4 loads (cur's data); this iter's 4 stay in flight
        if (pf) { asm volatile("s_waitcnt vmcnt(4)" ::: "memory"); }
        else    { asm volatile("s_waitcnt vmcnt(0)" ::: "memory"); }
        FENCE; __builtin_amdgcn_s_barrier(); FENCE;

        if (kt <= ktMax) {
            const unsigned short* KB_ = (const unsigned short*)(smem + cur * 16384);
            const unsigned short* VB_ = (const unsigned short*)(smem + cur * 16384 + 8192);
            int k0 = kt * 64;

            f32x16 s0_, s1_;
            __builtin_amdgcn_s_setprio(1);
            s0_ = mfma32(KF(0, 0), qf[0], zz);
            s0_ = mfma32(KF(0, 1), qf[1], s0_);
            s0_ = mfma32(KF(0, 2), qf[2], s0_);
            s0_ = mfma32(KF(0, 3), qf[3], s0_);
            s1_ = mfma32(KF(1, 0), qf[0], zz);
            s1_ = mfma32(KF(1, 1), qf[1], s1_);
            s1_ = mfma32(KF(1, 2), qf[2], s1_);
            s1_ = mfma32(KF(1, 3), qf[3], s1_);
            __builtin_amdgcn_s_setprio(0);

            if (kt == ktMax) {
                int qg_ = q0 + ql;
#pragma unroll
                for (int rr = 0; rr < 16; ++rr) {
                    int kof_ = k0 + 8 * (rr >> 2) + (rr & 3) + 4 * hi;
                    if (kof_ > qg_) s0_[rr] = -__builtin_inff();
                    if (kof_ + 32 > qg_) s1_[rr] = -__builtin_inff();
                }
            }

            float t_[8];
#pragma unroll
            for (int rr = 0; rr < 8; ++rr)
                t_[rr] = fmaxf(fmaxf(s0_[rr], s0_[rr + 8]), fmaxf(s1_[rr], s1_[rr + 8]));
#pragma unroll
            for (int rr = 0; rr < 4; ++rr) t_[rr] = fmaxf(t_[rr], t_[rr + 4]);
            float pm_ = fmaxf(fmaxf(t_[0], t_[1]), fmaxf(t_[2], t_[3]));
            pm_ = fmaxf(pm_, __shfl_xor(pm_, 32));

            float mn_ = mi;
            if (!__all((int)(pm_ <= mi + 8.f))) {  // defer-max
                mn_ = fmaxf(mi, pm_);
                float f_ = __builtin_amdgcn_exp2f(mi - mn_);
                mi = mn_;
                li *= f_;
                o0 *= f_;
                o1 *= f_;
            }
#pragma unroll
            for (int rr = 0; rr < 16; ++rr) {
                s0_[rr] = __builtin_amdgcn_exp2f(s0_[rr] - mn_);
                s1_[rr] = __builtin_amdgcn_exp2f(s1_[rr] - mn_);
            }
            float u_[8];
#pragma unroll
            for (int rr = 0; rr < 8; ++rr)
                u_[rr] = (s0_[rr] + s0_[rr + 8]) + (s1_[rr] + s1_[rr + 8]);
#pragma unroll
            for (int rr = 0; rr < 4; ++rr) u_[rr] += u_[rr + 4];
            float ps_ = (u_[0] + u_[1]) + (u_[2] + u_[3]);
            ps_ += __shfl_xor(ps_, 32);
            li += ps_;

#pragma unroll
            for (int K0_ = 0; K0_ < 2; ++K0_) {
#pragma unroll
                for (int h2_ = 0; h2_ < 2; ++h2_) {
                    float e0_ = K0_ ? s1_[8 * h2_ + 0] : s0_[8 * h2_ + 0];
                    float e1_ = K0_ ? s1_[8 * h2_ + 1] : s0_[8 * h2_ + 1];
                    float e2_ = K0_ ? s1_[8 * h2_ + 2] : s0_[8 * h2_ + 2];
                    float e3_ = K0_ ? s1_[8 * h2_ + 3] : s0_[8 * h2_ + 3];
                    float e4_ = K0_ ? s1_[8 * h2_ + 4] : s0_[8 * h2_ + 4];
                    float e5_ = K0_ ? s1_[8 * h2_ + 5] : s0_[8 * h2_ + 5];
                    float e6_ = K0_ ? s1_[8 * h2_ + 6] : s0_[8 * h2_ + 6];
                    float e7_ = K0_ ? s1_[8 * h2_ + 7] : s0_[8 * h2_ + 7];
                    unsigned a_, b_, c_, d_;
                    asm("v_cvt_pk_bf16_f32 %0, %1, %2" : "=v"(a_) : "v"(e0_), "v"(e1_));
                    asm("v_cvt_pk_bf16_f32 %0, %1, %2" : "=v"(b_) : "v"(e2_), "v"(e3_));
                    asm("v_cvt_pk_bf16_f32 %0, %1, %2" : "=v"(c_) : "v"(e4_), "v"(e5_));
                    asm("v_cvt_pk_bf16_f32 %0, %1, %2" : "=v"(d_) : "v"(e6_), "v"(e7_));
                    asm("v_permlane32_swap_b32 %0, %1" : "+v"(a_), "+v"(c_));
                    asm("v_permlane32_swap_b32 %0, %1" : "+v"(b_), "+v"(d_));
                    union { unsigned u[4]; bf16x8 v; } pf_;
                    pf_.u[0] = a_; pf_.u[1] = b_; pf_.u[2] = c_; pf_.u[3] = d_;
                    __builtin_amdgcn_s_setprio(1);
                    o0 = mfma32(VF(0, K0_ * 2 + h2_), pf_.v, o0);
                    o1 = mfma32(VF(1, K0_ * 2 + h2_), pf_.v, o1);
                    __builtin_amdgcn_s_setprio(0);
                }
            }
        }
        asm volatile("s_waitcnt lgkmcnt(0)" ::: "memory");
        FENCE; __builtin_amdgcn_s_barrier(); FENCE;  // reads of cur done; no vm drain
    }
#undef KF
#undef VF

    // epilogue: O^T[d][q]: q = q0+ql, d = dblk*32 + 8a + i + 4hi
    int bb = bh >> 4, h = bh & 15;
    float iv = 1.0f / li;
#pragma unroll
    for (int dblk = 0; dblk < 2; ++dblk) {
#pragma unroll
        for (int a = 0; a < 4; ++a) {
            u16x4 wv;
#pragma unroll
            for (int i = 0; i < 4; ++i)
                wv[i] = f2b((dblk ? o1[4 * a + i] : o0[4 * a + i]) * iv);
            int dq = dblk * 32 + 8 * a + 4 * hi;
            *(u16x4*)&Yb[((size_t)(bb * T_SEQ + q0 + ql)) * CDIM + h * HD + dq] = wv;
        }
    }
}

// ---------------- launch ----------------
extern "C" void kernel_launch(void* const* d_in, const int* in_sizes, int n_in,
                              void* d_out, int out_size, void* d_ws, size_t ws_size,
                              hipStream_t stream) {
    const float* x      = (const float*)d_in[0];
    const float* w_attn = (const float*)d_in[1];
    const float* b_attn = (const float*)d_in[2];
    const float* w_proj = (const float*)d_in[3];
    const float* b_proj = (const float*)d_in[4];
    float* out = (float*)d_out;

    // workspace layout (bytes):
    //   0         xb  : x bf16 [8192][1024]         16,777,216  (reused as yb)
    //   16777216  wTa : w_attn^T bf16 [3072][1024]   6,291,456
    //   23068672  wTp : w_proj^T bf16 [1024][1024]   2,097,152
    //   25165824  qb  : [64][2048][64] bf16         16,777,216  (pre-scaled by QSCALE)
    //   41943040  kb  : [64][2048][64] bf16         16,777,216
    //   58720256  vTb : [64][64][2048] bf16         16,777,216  (V^T, written by GEMM1)
    char* ws = (char*)d_ws;
    unsigned short* xb  = (unsigned short*)(ws);
    unsigned short* wTa = (unsigned short*)(ws + 16777216);
    unsigned short* wTp = (unsigned short*)(ws + 23068672);
    unsigned short* qb  = (unsigned short*)(ws + 25165824);
    unsigned short* kb  = (unsigned short*)(ws + 41943040);
    unsigned short* vTb = (unsigned short*)(ws + 58720256);
    unsigned short* yb  = xb;  // alias: xb dead after GEMM1

    // fused prep: blocks [0,1024)=cast, [1024,4096)=w_attn^T, [4096,5120)=w_proj^T
    prep_kernel<<<dim3(5120), 256, 0, stream>>>(x, w_attn, w_proj, xb, wTa, wTp);

    // QKV GEMM: 1536 blocks, 24KB LDS -> 6 blocks/CU, zero tail
    gemm_qkv_kernel<<<dim3(3072 / 128, 8192 / 128), 256, 0, stream>>>(
        xb, wTa, b_attn, qb, kb, vTb, 8192, 3072, 1024);

    // flash attention: 1024 balanced blocks x 4 waves
    attn32_kernel<<<dim3(1024), 256, 0, stream>>>(qb, kb, vTb, yb);

    // proj GEMM -> fp32 out
    gemm_proj_kernel<<<dim3(1024 / 128, 8192 / 128), 256, 0, stream>>>(
        yb, wTp, b_proj, out, 8192, 1024, 1024);
}

// Round 11
// 168.264 us; speedup vs baseline: 1.1791x; 1.0031x over previous
//
#include <hip/hip_runtime.h>

// CausalSelfAttention: B=4, T=2048, C=1024, H=16, hd=64
// fused prep, QKV GEMM (128^2, A-single/B-dbuf 24KB = 6 blocks/CU, counted vmcnt,
// conflict-free (row>>1)&3 LDS swizzle), 32x32-MFMA swapped-QK^T flash attention, proj GEMM

#define T_SEQ 2048
#define NB 4
#define NH 16
#define CDIM 1024
#define HD 64
#define BH (NB * NH)
#define QSCALE 0.1803368801111204f  // 0.125 * log2(e)

typedef float f32x4 __attribute__((ext_vector_type(4)));
typedef float f32x16 __attribute__((ext_vector_type(16)));
typedef __bf16 bf16x8 __attribute__((ext_vector_type(8)));
typedef unsigned short u16x8 __attribute__((ext_vector_type(8)));
typedef unsigned short u16x4 __attribute__((ext_vector_type(4)));

__device__ __forceinline__ unsigned short f2b(float f) {
    union { float f; unsigned u; } v; v.f = f;
    unsigned u = v.u;
    u += 0x7FFFu + ((u >> 16) & 1u);   // round-to-nearest-even
    return (unsigned short)(u >> 16);
}

__device__ __forceinline__ f32x4 fzero4() {
    f32x4 z; z[0] = 0.f; z[1] = 0.f; z[2] = 0.f; z[3] = 0.f; return z;
}

__device__ __forceinline__ f32x4 mfma16(bf16x8 a, bf16x8 b, f32x4 c) {
    return __builtin_amdgcn_mfma_f32_16x16x32_bf16(a, b, c, 0, 0, 0);
}

__device__ __forceinline__ f32x16 mfma32(bf16x8 a, bf16x8 b, f32x16 c) {
    return __builtin_amdgcn_mfma_f32_32x32x16_bf16(a, b, c, 0, 0, 0);
}

// async global->LDS, 16B/lane; LDS dest = wave-uniform base + lane*16 (HW rule)
__device__ __forceinline__ void gld16(const void* gp, void* lp) {
    __builtin_amdgcn_global_load_lds(
        (const __attribute__((address_space(1))) unsigned int*)gp,
        (__attribute__((address_space(3))) unsigned int*)lp, 16, 0, 0);
}

#define FENCE asm volatile("" ::: "memory")

// ---------------- fused prep: cast x, transpose w_attn, transpose w_proj ----------------
__device__ __forceinline__ void transpose_tile(
        const float* __restrict__ in, unsigned short* __restrict__ out,
        int R, int C, int bx, int by) {
    __shared__ unsigned short tile[32][33];
    int tx = threadIdx.x & 31, ty = threadIdx.x >> 5;
    int c0 = bx * 32, r0 = by * 32;
#pragma unroll
    for (int rr = ty; rr < 32; rr += 8)
        tile[rr][tx] = f2b(in[(size_t)(r0 + rr) * C + c0 + tx]);
    __syncthreads();
#pragma unroll
    for (int rr = ty; rr < 32; rr += 8)
        out[(size_t)(c0 + rr) * R + r0 + tx] = tile[tx][rr];
}

__global__ __launch_bounds__(256) void prep_kernel(
        const float* __restrict__ x, const float* __restrict__ wa,
        const float* __restrict__ wp, unsigned short* __restrict__ xb,
        unsigned short* __restrict__ wTa, unsigned short* __restrict__ wTp) {
    int b = blockIdx.x;
    if (b < 1024) {
        int n8 = (NB * T_SEQ * CDIM) / 8;
        for (int i = b * 256 + threadIdx.x; i < n8; i += 1024 * 256) {
            const float4* p = reinterpret_cast<const float4*>(x) + (size_t)i * 2;
            float4 a = p[0], c = p[1];
            u16x8 o;
            o[0] = f2b(a.x); o[1] = f2b(a.y); o[2] = f2b(a.z); o[3] = f2b(a.w);
            o[4] = f2b(c.x); o[5] = f2b(c.y); o[6] = f2b(c.z); o[7] = f2b(c.w);
            *(reinterpret_cast<u16x8*>(xb) + i) = o;
        }
    } else if (b < 1024 + 3072) {
        int t = b - 1024;   // w_attn [1024][3072]: 96 x 32 tiles
        transpose_tile(wa, wTa, 1024, 3072, t % 96, t / 96);
    } else {
        int t = b - 4096;   // w_proj [1024][1024]: 32 x 32 tiles
        transpose_tile(wp, wTp, 1024, 1024, t % 32, t / 32);
    }
}

// ---------------- QKV GEMM: 128^2, A-single + B-dbuf (24KB -> 6 blocks/CU) ----------------
// Conflict-free LDS swizzle (round-8-proven): 16B-slot s' = s ^ ((row>>1)&3).
// Bank = (row&1)*16 + s'*4: 16 lanes -> 8 spans x 2-way (free). Staged with
// inverse-swizzled global source (involution, both-sides rule).
__global__ __launch_bounds__(256) void gemm_qkv_kernel(
        const unsigned short* __restrict__ A, const unsigned short* __restrict__ Bt,
        const float* __restrict__ bias,
        unsigned short* __restrict__ q_out, unsigned short* __restrict__ k_out,
        unsigned short* __restrict__ v_out, int M, int N, int K) {
    __shared__ alignas(16) unsigned short As[128 * 32];     // 8KB single
    __shared__ alignas(16) unsigned short Bs[2][128 * 32];  // 16KB dbuf

    int tid = threadIdx.x;
    int wid = tid >> 6, lane = tid & 63;
    int g = lane >> 4, lc = lane & 15;
    int wr = (wid >> 1) * 64, wc = (wid & 1) * 64;
    int m0 = blockIdx.y * 128, n0 = blockIdx.x * 128;

    f32x4 acc[4][4];
#pragma unroll
    for (int m = 0; m < 4; ++m)
#pragma unroll
        for (int n = 0; n < 4; ++n) acc[m][n] = fzero4();

    int srow = tid >> 2;
    int scol = ((tid & 3) ^ ((srow >> 1) & 3)) * 8;  // inverse-swizzled source col
    const unsigned short* Ap = A + (size_t)(m0 + srow) * K + scol;
    const unsigned short* Bp = Bt + (size_t)(n0 + srow) * K + scol;
    int ldst = (wid * 16) * 32;
    int ldst2 = (64 + wid * 16) * 32;

#define STAGE_A(KOFF) {                                    \
        gld16(Ap + (KOFF), &As[ldst]);                     \
        gld16(Ap + (size_t)64 * K + (KOFF), &As[ldst2]); }
#define STAGE_B(BUF, KOFF) {                                       \
        gld16(Bp + (KOFF), &Bs[BUF][ldst]);                        \
        gld16(Bp + (size_t)64 * K + (KOFF), &Bs[BUF][ldst2]); }

    STAGE_B(0, 0)    // B(0)
    STAGE_A(0)       // A(0)
    STAGE_B(1, 32)   // B(1)

    int swz8 = (g ^ ((lc >> 1) & 3)) * 8;  // read slot swizzle ((row>>1)&3 == (lc>>1)&3)

    int nk = K >> 5;
    for (int it = 0; it < nk; ++it) {
        if (it + 1 < nk) { asm volatile("s_waitcnt vmcnt(2)" ::: "memory"); }
        else             { asm volatile("s_waitcnt vmcnt(0)" ::: "memory"); }
        FENCE; __builtin_amdgcn_s_barrier(); FENCE;  // A(it), B(it) visible

        bf16x8 af[4], bfr[4];
        const unsigned short* Bb = Bs[it & 1];
#pragma unroll
        for (int m = 0; m < 4; ++m)
            af[m] = *(const bf16x8*)&As[(wr + m * 16 + lc) * 32 + swz8];
#pragma unroll
        for (int n = 0; n < 4; ++n)
            bfr[n] = *(const bf16x8*)&Bb[(wc + n * 16 + lc) * 32 + swz8];

        __builtin_amdgcn_s_setprio(1);
#pragma unroll
        for (int m = 0; m < 4; ++m)
#pragma unroll
            for (int n = 0; n < 4; ++n)
                acc[m][n] = mfma16(af[m], bfr[n], acc[m][n]);
        __builtin_amdgcn_s_setprio(0);

        asm volatile("s_waitcnt lgkmcnt(0)" ::: "memory");
        FENCE; __builtin_amdgcn_s_barrier(); FENCE;  // all reads consumed
        if (it + 1 < nk) STAGE_A((it + 1) << 5)
        if (it + 2 < nk) STAGE_B(it & 1, (it + 2) << 5)
    }
#undef STAGE_A
#undef STAGE_B

    // epilogue: scatter q (scaled), k row-major; v transposed per head
#pragma unroll
    for (int m = 0; m < 4; ++m) {
        int rowb = m0 + wr + m * 16 + g * 4;
#pragma unroll
        for (int n = 0; n < 4; ++n) {
            int col = n0 + wc + n * 16 + lc;
            float bv = bias[col];
            int which = col >> 10;
            int c = col & 1023;
            int h = c >> 6, d = c & 63;
            int bh_ = (rowb >> 11) * NH + h;
            int tl = rowb & 2047;
            if (which == 2) {
                u16x4 vq;
#pragma unroll
                for (int i = 0; i < 4; ++i) vq[i] = f2b(acc[m][n][i] + bv);
                *(u16x4*)&v_out[(size_t)bh_ * (HD * T_SEQ) + (size_t)d * T_SEQ + tl] = vq;
            } else {
                unsigned short* dst = which ? k_out : q_out;
                float sc = which ? 1.0f : QSCALE;
#pragma unroll
                for (int i = 0; i < 4; ++i)
                    dst[((size_t)bh_ * T_SEQ + tl + i) * HD + d] =
                        f2b((acc[m][n][i] + bv) * sc);
            }
        }
    }
}

// ---------------- proj GEMM: 128^2 2-phase dbuf + counted vmcnt, fixed swizzle ----------
__global__ __launch_bounds__(256) void gemm_proj_kernel(
        const unsigned short* __restrict__ A, const unsigned short* __restrict__ Bt,
        const float* __restrict__ bias, float* __restrict__ outF, int M, int N, int K) {
    __shared__ alignas(16) unsigned short As[2][128 * 32];
    __shared__ alignas(16) unsigned short Bs[2][128 * 32];

    int tid = threadIdx.x;
    int wid = tid >> 6, lane = tid & 63;
    int g = lane >> 4, lc = lane & 15;
    int wr = (wid >> 1) * 64, wc = (wid & 1) * 64;
    int m0 = blockIdx.y * 128, n0 = blockIdx.x * 128;

    f32x4 acc[4][4];
#pragma unroll
    for (int m = 0; m < 4; ++m)
#pragma unroll
        for (int n = 0; n < 4; ++n) acc[m][n] = fzero4();

    int srow = tid >> 2;
    int scol = ((tid & 3) ^ ((srow >> 1) & 3)) * 8;
    const unsigned short* Ap = A + (size_t)(m0 + srow) * K + scol;
    const unsigned short* Bp = Bt + (size_t)(n0 + srow) * K + scol;
    int ldst = (wid * 16) * 32;
    int ldst2 = (64 + wid * 16) * 32;

#define GSTAGE(BUF, KOFF)                                      \
    gld16(Ap + (KOFF), &As[BUF][ldst]);                        \
    gld16(Ap + (size_t)64 * K + (KOFF), &As[BUF][ldst2]);      \
    gld16(Bp + (KOFF), &Bs[BUF][ldst]);                        \
    gld16(Bp + (size_t)64 * K + (KOFF), &Bs[BUF][ldst2]);

    GSTAGE(0, 0)
    GSTAGE(1, 32)

    int swz8 = (g ^ ((lc >> 1) & 3)) * 8;

    int nk = K >> 5;
    for (int it = 0; it < nk; ++it) {
        int cur = it & 1;
        if (it + 1 < nk) { asm volatile("s_waitcnt vmcnt(4)" ::: "memory"); }
        else             { asm volatile("s_waitcnt vmcnt(0)" ::: "memory"); }
        FENCE; __builtin_amdgcn_s_barrier(); FENCE;

        bf16x8 af[4], bfr[4];
#pragma unroll
        for (int m = 0; m < 4; ++m)
            af[m] = *(const bf16x8*)&As[cur][(wr + m * 16 + lc) * 32 + swz8];
#pragma unroll
        for (int n = 0; n < 4; ++n)
            bfr[n] = *(const bf16x8*)&Bs[cur][(wc + n * 16 + lc) * 32 + swz8];

        __builtin_amdgcn_s_setprio(1);
#pragma unroll
        for (int m = 0; m < 4; ++m)
#pragma unroll
            for (int n = 0; n < 4; ++n)
                acc[m][n] = mfma16(af[m], bfr[n], acc[m][n]);
        __builtin_amdgcn_s_setprio(0);

        FENCE; __builtin_amdgcn_s_barrier(); FENCE;
        if (it + 2 < nk) { GSTAGE(cur, (it + 2) << 5) }
    }
#undef GSTAGE

#pragma unroll
    for (int m = 0; m < 4; ++m) {
        int rowb = m0 + wr + m * 16 + g * 4;
#pragma unroll
        for (int n = 0; n < 4; ++n) {
            int col = n0 + wc + n * 16 + lc;
            float bv = bias[col];
#pragma unroll
            for (int i = 0; i < 4; ++i)
                outF[(size_t)(rowb + i) * N + col] = acc[m][n][i] + bv;
        }
    }
}

// ---------------- flash attention: 32x32 MFMA, swapped QK^T, counted-vmcnt sync ----------
__global__ __launch_bounds__(256, 4) void attn32_kernel(
        const unsigned short* __restrict__ Qb, const unsigned short* __restrict__ Kb,
        const unsigned short* __restrict__ Vt, unsigned short* __restrict__ Yb) {
    __shared__ alignas(16) char smem[32768];  // 2 x (K 8KB + V 8KB)

    int tid = threadIdx.x;
    int wid = tid >> 6, lane = tid & 63;
    int ql = lane & 31, hi = lane >> 5;
    int ql7 = ql & 7;

    // balanced XCD-aware mapping: id -> (bh, qg)
    int id = blockIdx.x;
    int x = id & 7;
    int k = id >> 3;
    int r = k >> 5;
    int c = k & 31;
    int hh = 2 * r + (c >> 4);
    int j = c & 15;
    int qg = (r & 1) ? (15 - j) : j;
    int bh = x * 8 + hh;
    size_t hb = (size_t)bh * (T_SEQ * HD);

    int qt = qg * 4 + wid;
    int q0 = qt * 32;
    int ktMax = qt >> 1;
    int ntB = 2 * qg + 2;

    bf16x8 qf[4];
    const unsigned short* Qp = Qb + hb + (size_t)(q0 + ql) * HD + hi * 8;
#pragma unroll
    for (int d = 0; d < 4; ++d) qf[d] = *(const bf16x8*)(Qp + d * 16);

    f32x16 zz;
#pragma unroll
    for (int rr = 0; rr < 16; ++rr) zz[rr] = 0.f;
    f32x16 o0 = zz, o1 = zz;
    float mi = -__builtin_inff(), li = 0.f;

    int r8 = lane >> 3;
    int sslot8 = ((lane & 7) ^ r8) * 8;
    const unsigned short* Kg = Kb + hb + (size_t)(wid * 16 + r8) * HD + sslot8;
    const unsigned short* Vg = Vt + hb + (size_t)(wid * 16 + r8) * T_SEQ + sslot8;

    // prologue: stage kt=0 into buf 0
    gld16(Kg, smem + wid * 2048);
    gld16(Kg + 8 * HD, smem + wid * 2048 + 1024);
    gld16(Vg, smem + 8192 + wid * 2048);
    gld16(Vg + 8 * T_SEQ, smem + 8192 + wid * 2048 + 1024);
    __syncthreads();

#define KF(K0, D) (*(const bf16x8*)&KB_[(((K0)*32 + ql) << 6) + ((((D)*2 + hi) ^ ql7) << 3)])
#define VF(DB, T) (*(const bf16x8*)&VB_[(((DB)*32 + ql) << 6) + ((((T)*2 + hi) ^ ql7) << 3)])

    for (int kt = 0; kt < ntB; ++kt) {
        int cur = kt & 1;
        bool pf = (kt + 1 < ntB);
        if (pf) {  // prefetch next tile into other buffer
            char* nb = smem + (cur ^ 1) * 16384;
            gld16(Kg + (size_t)(kt + 1) * 64 * HD, nb + wid * 2048);
            gld16(Kg + (size_t)((kt + 1) * 64 + 8) * HD, nb + wid * 2048 + 1024);
            gld16(Vg + (kt + 1) * 64, nb + 8192 + wid * 2048);
            gld16(Vg + (kt + 1) * 64 + 8 * T_SEQ, nb + 8192 + wid * 2048 + 1024);
        }
        if (pf) { asm volatile("s_waitcnt vmcnt(4)" ::: "memory"); }
        else    { asm volatile("s_waitcnt vmcnt(0)" ::: "memory"); }
        FENCE; __builtin_amdgcn_s_barrier(); FENCE;

        if (kt <= ktMax) {
            const unsigned short* KB_ = (const unsigned short*)(smem + cur * 16384);
            const unsigned short* VB_ = (const unsigned short*)(smem + cur * 16384 + 8192);
            int k0 = kt * 64;

            f32x16 s0_, s1_;
            __builtin_amdgcn_s_setprio(1);
            s0_ = mfma32(KF(0, 0), qf[0], zz);
            s0_ = mfma32(KF(0, 1), qf[1], s0_);
            s0_ = mfma32(KF(0, 2), qf[2], s0_);
            s0_ = mfma32(KF(0, 3), qf[3], s0_);
            s1_ = mfma32(KF(1, 0), qf[0], zz);
            s1_ = mfma32(KF(1, 1), qf[1], s1_);
            s1_ = mfma32(KF(1, 2), qf[2], s1_);
            s1_ = mfma32(KF(1, 3), qf[3], s1_);
            __builtin_amdgcn_s_setprio(0);

            if (kt == ktMax) {
                int qg_ = q0 + ql;
#pragma unroll
                for (int rr = 0; rr < 16; ++rr) {
                    int kof_ = k0 + 8 * (rr >> 2) + (rr & 3) + 4 * hi;
                    if (kof_ > qg_) s0_[rr] = -__builtin_inff();
                    if (kof_ + 32 > qg_) s1_[rr] = -__builtin_inff();
                }
            }

            float t_[8];
#pragma unroll
            for (int rr = 0; rr < 8; ++rr)
                t_[rr] = fmaxf(fmaxf(s0_[rr], s0_[rr + 8]), fmaxf(s1_[rr], s1_[rr + 8]));
#pragma unroll
            for (int rr = 0; rr < 4; ++rr) t_[rr] = fmaxf(t_[rr], t_[rr + 4]);
            float pm_ = fmaxf(fmaxf(t_[0], t_[1]), fmaxf(t_[2], t_[3]));
            pm_ = fmaxf(pm_, __shfl_xor(pm_, 32));

            float mn_ = mi;
            if (!__all((int)(pm_ <= mi + 8.f))) {  // defer-max
                mn_ = fmaxf(mi, pm_);
                float f_ = __builtin_amdgcn_exp2f(mi - mn_);
                mi = mn_;
                li *= f_;
                o0 *= f_;
                o1 *= f_;
            }
#pragma unroll
            for (int rr = 0; rr < 16; ++rr) {
                s0_[rr] = __builtin_amdgcn_exp2f(s0_[rr] - mn_);
                s1_[rr] = __builtin_amdgcn_exp2f(s1_[rr] - mn_);
            }
            float u_[8];
#pragma unroll
            for (int rr = 0; rr < 8; ++rr)
                u_[rr] = (s0_[rr] + s0_[rr + 8]) + (s1_[rr] + s1_[rr + 8]);
#pragma unroll
            for (int rr = 0; rr < 4; ++rr) u_[rr] += u_[rr + 4];
            float ps_ = (u_[0] + u_[1]) + (u_[2] + u_[3]);
            ps_ += __shfl_xor(ps_, 32);
            li += ps_;

#pragma unroll
            for (int K0_ = 0; K0_ < 2; ++K0_) {
#pragma unroll
                for (int h2_ = 0; h2_ < 2; ++h2_) {
                    float e0_ = K0_ ? s1_[8 * h2_ + 0] : s0_[8 * h2_ + 0];
                    float e1_ = K0_ ? s1_[8 * h2_ + 1] : s0_[8 * h2_ + 1];
                    float e2_ = K0_ ? s1_[8 * h2_ + 2] : s0_[8 * h2_ + 2];
                    float e3_ = K0_ ? s1_[8 * h2_ + 3] : s0_[8 * h2_ + 3];
                    float e4_ = K0_ ? s1_[8 * h2_ + 4] : s0_[8 * h2_ + 4];
                    float e5_ = K0_ ? s1_[8 * h2_ + 5] : s0_[8 * h2_ + 5];
                    float e6_ = K0_ ? s1_[8 * h2_ + 6] : s0_[8 * h2_ + 6];
                    float e7_ = K0_ ? s1_[8 * h2_ + 7] : s0_[8 * h2_ + 7];
                    unsigned a_, b_, c_, d_;
                    asm("v_cvt_pk_bf16_f32 %0, %1, %2" : "=v"(a_) : "v"(e0_), "v"(e1_));
                    asm("v_cvt_pk_bf16_f32 %0, %1, %2" : "=v"(b_) : "v"(e2_), "v"(e3_));
                    asm("v_cvt_pk_bf16_f32 %0, %1, %2" : "=v"(c_) : "v"(e4_), "v"(e5_));
                    asm("v_cvt_pk_bf16_f32 %0, %1, %2" : "=v"(d_) : "v"(e6_), "v"(e7_));
                    asm("v_permlane32_swap_b32 %0, %1" : "+v"(a_), "+v"(c_));
                    asm("v_permlane32_swap_b32 %0, %1" : "+v"(b_), "+v"(d_));
                    union { unsigned u[4]; bf16x8 v; } pf_;
                    pf_.u[0] = a_; pf_.u[1] = b_; pf_.u[2] = c_; pf_.u[3] = d_;
                    __builtin_amdgcn_s_setprio(1);
                    o0 = mfma32(VF(0, K0_ * 2 + h2_), pf_.v, o0);
                    o1 = mfma32(VF(1, K0_ * 2 + h2_), pf_.v, o1);
                    __builtin_amdgcn_s_setprio(0);
                }
            }
        }
        asm volatile("s_waitcnt lgkmcnt(0)" ::: "memory");
        FENCE; __builtin_amdgcn_s_barrier(); FENCE;  // reads of cur done; no vm drain
    }
#undef KF
#undef VF

    // epilogue: O^T[d][q]: q = q0+ql, d = dblk*32 + 8a + i + 4hi
    int bb = bh >> 4, h = bh & 15;
    float iv = 1.0f / li;
#pragma unroll
    for (int dblk = 0; dblk < 2; ++dblk) {
#pragma unroll
        for (int a = 0; a < 4; ++a) {
            u16x4 wv;
#pragma unroll
            for (int i = 0; i < 4; ++i)
                wv[i] = f2b((dblk ? o1[4 * a + i] : o0[4 * a + i]) * iv);
            int dq = dblk * 32 + 8 * a + 4 * hi;
            *(u16x4*)&Yb[((size_t)(bb * T_SEQ + q0 + ql)) * CDIM + h * HD + dq] = wv;
        }
    }
}

// ---------------- launch ----------------
extern "C" void kernel_launch(void* const* d_in, const int* in_sizes, int n_in,
                              void* d_out, int out_size, void* d_ws, size_t ws_size,
                              hipStream_t stream) {
    const float* x      = (const float*)d_in[0];
    const float* w_attn = (const float*)d_in[1];
    const float* b_attn = (const float*)d_in[2];
    const float* w_proj = (const float*)d_in[3];
    const float* b_proj = (const float*)d_in[4];
    float* out = (float*)d_out;

    // workspace layout (bytes):
    //   0         xb  : x bf16 [8192][1024]         16,777,216  (reused as yb)
    //   16777216  wTa : w_attn^T bf16 [3072][1024]   6,291,456
    //   23068672  wTp : w_proj^T bf16 [1024][1024]   2,097,152
    //   25165824  qb  : [64][2048][64] bf16         16,777,216  (pre-scaled by QSCALE)
    //   41943040  kb  : [64][2048][64] bf16         16,777,216
    //   58720256  vTb : [64][64][2048] bf16         16,777,216  (V^T, written by GEMM1)
    char* ws = (char*)d_ws;
    unsigned short* xb  = (unsigned short*)(ws);
    unsigned short* wTa = (unsigned short*)(ws + 16777216);
    unsigned short* wTp = (unsigned short*)(ws + 23068672);
    unsigned short* qb  = (unsigned short*)(ws + 25165824);
    unsigned short* kb  = (unsigned short*)(ws + 41943040);
    unsigned short* vTb = (unsigned short*)(ws + 58720256);
    unsigned short* yb  = xb;  // alias: xb dead after GEMM1

    // fused prep: blocks [0,1024)=cast, [1024,4096)=w_attn^T, [4096,5120)=w_proj^T
    prep_kernel<<<dim3(5120), 256, 0, stream>>>(x, w_attn, w_proj, xb, wTa, wTp);

    // QKV GEMM: 1536 blocks, 24KB LDS -> 6 blocks/CU, zero tail
    gemm_qkv_kernel<<<dim3(3072 / 128, 8192 / 128), 256, 0, stream>>>(
        xb, wTa, b_attn, qb, kb, vTb, 8192, 3072, 1024);

    // flash attention: 1024 balanced blocks x 4 waves
    attn32_kernel<<<dim3(1024), 256, 0, stream>>>(qb, kb, vTb, yb);

    // proj GEMM -> fp32 out
    gemm_proj_kernel<<<dim3(1024 / 128, 8192 / 128), 256, 0, stream>>>(
        yb, wTp, b_proj, out, 8192, 1024, 1024);
}

// Round 12
// 166.369 us; speedup vs baseline: 1.1926x; 1.0114x over previous
//
#include <hip/hip_runtime.h>

// CausalSelfAttention: B=4, T=2048, C=1024, H=16, hd=64
// fused prep, QKV GEMM (128^2, A-single/B-dbuf 24KB, counted vmcnt, conflict-free swizzle),
// 8-wave 32x32-MFMA swapped-QK^T flash attention (256 q-rows/block), proj GEMM

#define T_SEQ 2048
#define NB 4
#define NH 16
#define CDIM 1024
#define HD 64
#define BH (NB * NH)
#define QSCALE 0.1803368801111204f  // 0.125 * log2(e)

typedef float f32x4 __attribute__((ext_vector_type(4)));
typedef float f32x16 __attribute__((ext_vector_type(16)));
typedef __bf16 bf16x8 __attribute__((ext_vector_type(8)));
typedef unsigned short u16x8 __attribute__((ext_vector_type(8)));
typedef unsigned short u16x4 __attribute__((ext_vector_type(4)));

__device__ __forceinline__ unsigned short f2b(float f) {
    union { float f; unsigned u; } v; v.f = f;
    unsigned u = v.u;
    u += 0x7FFFu + ((u >> 16) & 1u);   // round-to-nearest-even
    return (unsigned short)(u >> 16);
}

__device__ __forceinline__ f32x4 fzero4() {
    f32x4 z; z[0] = 0.f; z[1] = 0.f; z[2] = 0.f; z[3] = 0.f; return z;
}

__device__ __forceinline__ f32x4 mfma16(bf16x8 a, bf16x8 b, f32x4 c) {
    return __builtin_amdgcn_mfma_f32_16x16x32_bf16(a, b, c, 0, 0, 0);
}

__device__ __forceinline__ f32x16 mfma32(bf16x8 a, bf16x8 b, f32x16 c) {
    return __builtin_amdgcn_mfma_f32_32x32x16_bf16(a, b, c, 0, 0, 0);
}

// async global->LDS, 16B/lane; LDS dest = wave-uniform base + lane*16 (HW rule)
__device__ __forceinline__ void gld16(const void* gp, void* lp) {
    __builtin_amdgcn_global_load_lds(
        (const __attribute__((address_space(1))) unsigned int*)gp,
        (__attribute__((address_space(3))) unsigned int*)lp, 16, 0, 0);
}

#define FENCE asm volatile("" ::: "memory")

// ---------------- fused prep: cast x, transpose w_attn, transpose w_proj ----------------
__device__ __forceinline__ void transpose_tile(
        const float* __restrict__ in, unsigned short* __restrict__ out,
        int R, int C, int bx, int by) {
    __shared__ unsigned short tile[32][33];
    int tx = threadIdx.x & 31, ty = threadIdx.x >> 5;
    int c0 = bx * 32, r0 = by * 32;
#pragma unroll
    for (int rr = ty; rr < 32; rr += 8)
        tile[rr][tx] = f2b(in[(size_t)(r0 + rr) * C + c0 + tx]);
    __syncthreads();
#pragma unroll
    for (int rr = ty; rr < 32; rr += 8)
        out[(size_t)(c0 + rr) * R + r0 + tx] = tile[tx][rr];
}

__global__ __launch_bounds__(256) void prep_kernel(
        const float* __restrict__ x, const float* __restrict__ wa,
        const float* __restrict__ wp, unsigned short* __restrict__ xb,
        unsigned short* __restrict__ wTa, unsigned short* __restrict__ wTp) {
    int b = blockIdx.x;
    if (b < 1024) {
        int n8 = (NB * T_SEQ * CDIM) / 8;
        for (int i = b * 256 + threadIdx.x; i < n8; i += 1024 * 256) {
            const float4* p = reinterpret_cast<const float4*>(x) + (size_t)i * 2;
            float4 a = p[0], c = p[1];
            u16x8 o;
            o[0] = f2b(a.x); o[1] = f2b(a.y); o[2] = f2b(a.z); o[3] = f2b(a.w);
            o[4] = f2b(c.x); o[5] = f2b(c.y); o[6] = f2b(c.z); o[7] = f2b(c.w);
            *(reinterpret_cast<u16x8*>(xb) + i) = o;
        }
    } else if (b < 1024 + 3072) {
        int t = b - 1024;   // w_attn [1024][3072]: 96 x 32 tiles
        transpose_tile(wa, wTa, 1024, 3072, t % 96, t / 96);
    } else {
        int t = b - 4096;   // w_proj [1024][1024]: 32 x 32 tiles
        transpose_tile(wp, wTp, 1024, 1024, t % 32, t / 32);
    }
}

// ---------------- QKV GEMM: 128^2, A-single + B-dbuf (24KB -> 6 blocks/CU) ----------------
__global__ __launch_bounds__(256) void gemm_qkv_kernel(
        const unsigned short* __restrict__ A, const unsigned short* __restrict__ Bt,
        const float* __restrict__ bias,
        unsigned short* __restrict__ q_out, unsigned short* __restrict__ k_out,
        unsigned short* __restrict__ v_out, int M, int N, int K) {
    __shared__ alignas(16) unsigned short As[128 * 32];     // 8KB single
    __shared__ alignas(16) unsigned short Bs[2][128 * 32];  // 16KB dbuf

    int tid = threadIdx.x;
    int wid = tid >> 6, lane = tid & 63;
    int g = lane >> 4, lc = lane & 15;
    int wr = (wid >> 1) * 64, wc = (wid & 1) * 64;
    int m0 = blockIdx.y * 128, n0 = blockIdx.x * 128;

    f32x4 acc[4][4];
#pragma unroll
    for (int m = 0; m < 4; ++m)
#pragma unroll
        for (int n = 0; n < 4; ++n) acc[m][n] = fzero4();

    int srow = tid >> 2;
    int scol = ((tid & 3) ^ ((srow >> 1) & 3)) * 8;  // inverse-swizzled source col
    const unsigned short* Ap = A + (size_t)(m0 + srow) * K + scol;
    const unsigned short* Bp = Bt + (size_t)(n0 + srow) * K + scol;
    int ldst = (wid * 16) * 32;
    int ldst2 = (64 + wid * 16) * 32;

#define STAGE_A(KOFF) {                                    \
        gld16(Ap + (KOFF), &As[ldst]);                     \
        gld16(Ap + (size_t)64 * K + (KOFF), &As[ldst2]); }
#define STAGE_B(BUF, KOFF) {                                       \
        gld16(Bp + (KOFF), &Bs[BUF][ldst]);                        \
        gld16(Bp + (size_t)64 * K + (KOFF), &Bs[BUF][ldst2]); }

    STAGE_B(0, 0)    // B(0)
    STAGE_A(0)       // A(0)
    STAGE_B(1, 32)   // B(1)

    int swz8 = (g ^ ((lc >> 1) & 3)) * 8;  // read slot swizzle ((row>>1)&3 == (lc>>1)&3)

    int nk = K >> 5;
    for (int it = 0; it < nk; ++it) {
        if (it + 1 < nk) { asm volatile("s_waitcnt vmcnt(2)" ::: "memory"); }
        else             { asm volatile("s_waitcnt vmcnt(0)" ::: "memory"); }
        FENCE; __builtin_amdgcn_s_barrier(); FENCE;  // A(it), B(it) visible

        bf16x8 af[4], bfr[4];
        const unsigned short* Bb = Bs[it & 1];
#pragma unroll
        for (int m = 0; m < 4; ++m)
            af[m] = *(const bf16x8*)&As[(wr + m * 16 + lc) * 32 + swz8];
#pragma unroll
        for (int n = 0; n < 4; ++n)
            bfr[n] = *(const bf16x8*)&Bb[(wc + n * 16 + lc) * 32 + swz8];

        __builtin_amdgcn_s_setprio(1);
#pragma unroll
        for (int m = 0; m < 4; ++m)
#pragma unroll
            for (int n = 0; n < 4; ++n)
                acc[m][n] = mfma16(af[m], bfr[n], acc[m][n]);
        __builtin_amdgcn_s_setprio(0);

        asm volatile("s_waitcnt lgkmcnt(0)" ::: "memory");
        FENCE; __builtin_amdgcn_s_barrier(); FENCE;  // all reads consumed
        if (it + 1 < nk) STAGE_A((it + 1) << 5)
        if (it + 2 < nk) STAGE_B(it & 1, (it + 2) << 5)
    }
#undef STAGE_A
#undef STAGE_B

    // epilogue: scatter q (scaled), k row-major; v transposed per head
#pragma unroll
    for (int m = 0; m < 4; ++m) {
        int rowb = m0 + wr + m * 16 + g * 4;
#pragma unroll
        for (int n = 0; n < 4; ++n) {
            int col = n0 + wc + n * 16 + lc;
            float bv = bias[col];
            int which = col >> 10;
            int c = col & 1023;
            int h = c >> 6, d = c & 63;
            int bh_ = (rowb >> 11) * NH + h;
            int tl = rowb & 2047;
            if (which == 2) {
                u16x4 vq;
#pragma unroll
                for (int i = 0; i < 4; ++i) vq[i] = f2b(acc[m][n][i] + bv);
                *(u16x4*)&v_out[(size_t)bh_ * (HD * T_SEQ) + (size_t)d * T_SEQ + tl] = vq;
            } else {
                unsigned short* dst = which ? k_out : q_out;
                float sc = which ? 1.0f : QSCALE;
#pragma unroll
                for (int i = 0; i < 4; ++i)
                    dst[((size_t)bh_ * T_SEQ + tl + i) * HD + d] =
                        f2b((acc[m][n][i] + bv) * sc);
            }
        }
    }
}

// ---------------- proj GEMM: 128^2 2-phase dbuf + counted vmcnt ----------
__global__ __launch_bounds__(256) void gemm_proj_kernel(
        const unsigned short* __restrict__ A, const unsigned short* __restrict__ Bt,
        const float* __restrict__ bias, float* __restrict__ outF, int M, int N, int K) {
    __shared__ alignas(16) unsigned short As[2][128 * 32];
    __shared__ alignas(16) unsigned short Bs[2][128 * 32];

    int tid = threadIdx.x;
    int wid = tid >> 6, lane = tid & 63;
    int g = lane >> 4, lc = lane & 15;
    int wr = (wid >> 1) * 64, wc = (wid & 1) * 64;
    int m0 = blockIdx.y * 128, n0 = blockIdx.x * 128;

    f32x4 acc[4][4];
#pragma unroll
    for (int m = 0; m < 4; ++m)
#pragma unroll
        for (int n = 0; n < 4; ++n) acc[m][n] = fzero4();

    int srow = tid >> 2;
    int scol = ((tid & 3) ^ ((srow >> 1) & 3)) * 8;
    const unsigned short* Ap = A + (size_t)(m0 + srow) * K + scol;
    const unsigned short* Bp = Bt + (size_t)(n0 + srow) * K + scol;
    int ldst = (wid * 16) * 32;
    int ldst2 = (64 + wid * 16) * 32;

#define GSTAGE(BUF, KOFF)                                      \
    gld16(Ap + (KOFF), &As[BUF][ldst]);                        \
    gld16(Ap + (size_t)64 * K + (KOFF), &As[BUF][ldst2]);      \
    gld16(Bp + (KOFF), &Bs[BUF][ldst]);                        \
    gld16(Bp + (size_t)64 * K + (KOFF), &Bs[BUF][ldst2]);

    GSTAGE(0, 0)
    GSTAGE(1, 32)

    int swz8 = (g ^ ((lc >> 1) & 3)) * 8;

    int nk = K >> 5;
    for (int it = 0; it < nk; ++it) {
        int cur = it & 1;
        if (it + 1 < nk) { asm volatile("s_waitcnt vmcnt(4)" ::: "memory"); }
        else             { asm volatile("s_waitcnt vmcnt(0)" ::: "memory"); }
        FENCE; __builtin_amdgcn_s_barrier(); FENCE;

        bf16x8 af[4], bfr[4];
#pragma unroll
        for (int m = 0; m < 4; ++m)
            af[m] = *(const bf16x8*)&As[cur][(wr + m * 16 + lc) * 32 + swz8];
#pragma unroll
        for (int n = 0; n < 4; ++n)
            bfr[n] = *(const bf16x8*)&Bs[cur][(wc + n * 16 + lc) * 32 + swz8];

        __builtin_amdgcn_s_setprio(1);
#pragma unroll
        for (int m = 0; m < 4; ++m)
#pragma unroll
            for (int n = 0; n < 4; ++n)
                acc[m][n] = mfma16(af[m], bfr[n], acc[m][n]);
        __builtin_amdgcn_s_setprio(0);

        FENCE; __builtin_amdgcn_s_barrier(); FENCE;
        if (it + 2 < nk) { GSTAGE(cur, (it + 2) << 5) }
    }
#undef GSTAGE

#pragma unroll
    for (int m = 0; m < 4; ++m) {
        int rowb = m0 + wr + m * 16 + g * 4;
#pragma unroll
        for (int n = 0; n < 4; ++n) {
            int col = n0 + wc + n * 16 + lc;
            float bv = bias[col];
#pragma unroll
            for (int i = 0; i < 4; ++i)
                outF[(size_t)(rowb + i) * N + col] = acc[m][n][i] + bv;
        }
    }
}

// ---------------- flash attention: 8 waves/block, 256 q-rows, swapped QK^T ----------------
// 512 blocks x 512 thr. Block = (head, g): q-tiles g*8 + wid (32 rows each, wid 0..7).
// Each staged 16KB KV tile feeds 8 waves (vs 4 before): -47% staging & barrier iters.
// Per-XCD dispatch rounds flip g <-> 7-g so each CU's 2 resident blocks sum to 36 iters.
__global__ __launch_bounds__(512, 4) void attn32_kernel(
        const unsigned short* __restrict__ Qb, const unsigned short* __restrict__ Kb,
        const unsigned short* __restrict__ Vt, unsigned short* __restrict__ Yb) {
    __shared__ alignas(16) char smem[32768];  // 2 x (K 8KB + V 8KB)

    int tid = threadIdx.x;
    int wid = tid >> 6, lane = tid & 63;
    int ql = lane & 31, hi = lane >> 5;
    int ql7 = ql & 7;

    // mapping: id -> (bh, g); second intra-XCD round flips g for CU balance
    int id = blockIdx.x;
    int x = id & 7;          // XCD
    int k = id >> 3;         // 0..63 within XCD
    int g = k & 7;
    if (k & 32) g = 7 - g;
    int bh = x * 8 + (k >> 3);
    size_t hb = (size_t)bh * (T_SEQ * HD);

    int qt = g * 8 + wid;             // this wave's 32-row q-tile
    int q0 = qt * 32;
    int ktMax = qt >> 1;              // last (diagonal) KV tile for this wave
    int ntB = 4 * g + 4;              // block's KV tile count (max over waves)

    // persistent Q B-frag (col=q=ql, elems d = dstep*16 + hi*8 + e)
    bf16x8 qf[4];
    const unsigned short* Qp = Qb + hb + (size_t)(q0 + ql) * HD + hi * 8;
#pragma unroll
    for (int d = 0; d < 4; ++d) qf[d] = *(const bf16x8*)(Qp + d * 16);

    f32x16 zz;
#pragma unroll
    for (int rr = 0; rr < 16; ++rr) zz[rr] = 0.f;
    f32x16 o0 = zz, o1 = zz;
    float mi = -__builtin_inff(), li = 0.f;

    // staging: 512 threads, 1 gld16 each for K and V; wave w covers rows [8w, 8w+8)
    int r8 = lane >> 3;
    int sslot8 = ((lane & 7) ^ r8) * 8;  // pre-swizzled source slot
    const unsigned short* Kg = Kb + hb + (size_t)(wid * 8 + r8) * HD + sslot8;
    const unsigned short* Vg = Vt + hb + (size_t)(wid * 8 + r8) * T_SEQ + sslot8;

    // prologue: stage kt=0 into buf 0
    gld16(Kg, smem + wid * 1024);
    gld16(Vg, smem + 8192 + wid * 1024);
    __syncthreads();

#define KF(K0, D) (*(const bf16x8*)&KB_[(((K0)*32 + ql) << 6) + ((((D)*2 + hi) ^ ql7) << 3)])
#define VF(DB, T) (*(const bf16x8*)&VB_[(((DB)*32 + ql) << 6) + ((((T)*2 + hi) ^ ql7) << 3)])

    for (int kt = 0; kt < ntB; ++kt) {
        int cur = kt & 1;
        bool pf = (kt + 1 < ntB);
        if (pf) {  // prefetch next tile into other buffer
            char* nb = smem + (cur ^ 1) * 16384;
            gld16(Kg + (size_t)(kt + 1) * 64 * HD, nb + wid * 1024);
            gld16(Vg + (kt + 1) * 64, nb + 8192 + wid * 1024);
        }
        // wait only the PREVIOUS iter's loads (cur's data); this iter's stay in flight
        if (pf) { asm volatile("s_waitcnt vmcnt(2)" ::: "memory"); }
        else    { asm volatile("s_waitcnt vmcnt(0)" ::: "memory"); }
        FENCE; __builtin_amdgcn_s_barrier(); FENCE;

        if (kt <= ktMax) {
            const unsigned short* KB_ = (const unsigned short*)(smem + cur * 16384);
            const unsigned short* VB_ = (const unsigned short*)(smem + cur * 16384 + 8192);
            int k0 = kt * 64;

            f32x16 s0_, s1_;
            __builtin_amdgcn_s_setprio(1);
            s0_ = mfma32(KF(0, 0), qf[0], zz);
            s0_ = mfma32(KF(0, 1), qf[1], s0_);
            s0_ = mfma32(KF(0, 2), qf[2], s0_);
            s0_ = mfma32(KF(0, 3), qf[3], s0_);
            s1_ = mfma32(KF(1, 0), qf[0], zz);
            s1_ = mfma32(KF(1, 1), qf[1], s1_);
            s1_ = mfma32(KF(1, 2), qf[2], s1_);
            s1_ = mfma32(KF(1, 3), qf[3], s1_);
            __builtin_amdgcn_s_setprio(0);

            if (kt == ktMax) {  // causal mask, diagonal tile only
                int qg_ = q0 + ql;
#pragma unroll
                for (int rr = 0; rr < 16; ++rr) {
                    int kof_ = k0 + 8 * (rr >> 2) + (rr & 3) + 4 * hi;
                    if (kof_ > qg_) s0_[rr] = -__builtin_inff();
                    if (kof_ + 32 > qg_) s1_[rr] = -__builtin_inff();
                }
            }

            // lane-local row max (exp2 domain; q pre-scaled by 0.125*log2e)
            float t_[8];
#pragma unroll
            for (int rr = 0; rr < 8; ++rr)
                t_[rr] = fmaxf(fmaxf(s0_[rr], s0_[rr + 8]), fmaxf(s1_[rr], s1_[rr + 8]));
#pragma unroll
            for (int rr = 0; rr < 4; ++rr) t_[rr] = fmaxf(t_[rr], t_[rr + 4]);
            float pm_ = fmaxf(fmaxf(t_[0], t_[1]), fmaxf(t_[2], t_[3]));
            pm_ = fmaxf(pm_, __shfl_xor(pm_, 32));

            float mn_ = mi;
            if (!__all((int)(pm_ <= mi + 8.f))) {  // defer-max
                mn_ = fmaxf(mi, pm_);
                float f_ = __builtin_amdgcn_exp2f(mi - mn_);
                mi = mn_;
                li *= f_;
                o0 *= f_;
                o1 *= f_;
            }
#pragma unroll
            for (int rr = 0; rr < 16; ++rr) {
                s0_[rr] = __builtin_amdgcn_exp2f(s0_[rr] - mn_);
                s1_[rr] = __builtin_amdgcn_exp2f(s1_[rr] - mn_);
            }
            float u_[8];
#pragma unroll
            for (int rr = 0; rr < 8; ++rr)
                u_[rr] = (s0_[rr] + s0_[rr + 8]) + (s1_[rr] + s1_[rr + 8]);
#pragma unroll
            for (int rr = 0; rr < 4; ++rr) u_[rr] += u_[rr + 4];
            float ps_ = (u_[0] + u_[1]) + (u_[2] + u_[3]);
            ps_ += __shfl_xor(ps_, 32);
            li += ps_;

            // P -> PV B-frag via cvt_pk + permlane32_swap, then O += V^T P^T
#pragma unroll
            for (int K0_ = 0; K0_ < 2; ++K0_) {
#pragma unroll
                for (int h2_ = 0; h2_ < 2; ++h2_) {
                    float e0_ = K0_ ? s1_[8 * h2_ + 0] : s0_[8 * h2_ + 0];
                    float e1_ = K0_ ? s1_[8 * h2_ + 1] : s0_[8 * h2_ + 1];
                    float e2_ = K0_ ? s1_[8 * h2_ + 2] : s0_[8 * h2_ + 2];
                    float e3_ = K0_ ? s1_[8 * h2_ + 3] : s0_[8 * h2_ + 3];
                    float e4_ = K0_ ? s1_[8 * h2_ + 4] : s0_[8 * h2_ + 4];
                    float e5_ = K0_ ? s1_[8 * h2_ + 5] : s0_[8 * h2_ + 5];
                    float e6_ = K0_ ? s1_[8 * h2_ + 6] : s0_[8 * h2_ + 6];
                    float e7_ = K0_ ? s1_[8 * h2_ + 7] : s0_[8 * h2_ + 7];
                    unsigned a_, b_, c_, d_;
                    asm("v_cvt_pk_bf16_f32 %0, %1, %2" : "=v"(a_) : "v"(e0_), "v"(e1_));
                    asm("v_cvt_pk_bf16_f32 %0, %1, %2" : "=v"(b_) : "v"(e2_), "v"(e3_));
                    asm("v_cvt_pk_bf16_f32 %0, %1, %2" : "=v"(c_) : "v"(e4_), "v"(e5_));
                    asm("v_cvt_pk_bf16_f32 %0, %1, %2" : "=v"(d_) : "v"(e6_), "v"(e7_));
                    asm("v_permlane32_swap_b32 %0, %1" : "+v"(a_), "+v"(c_));
                    asm("v_permlane32_swap_b32 %0, %1" : "+v"(b_), "+v"(d_));
                    union { unsigned u[4]; bf16x8 v; } pf_;
                    pf_.u[0] = a_; pf_.u[1] = b_; pf_.u[2] = c_; pf_.u[3] = d_;
                    __builtin_amdgcn_s_setprio(1);
                    o0 = mfma32(VF(0, K0_ * 2 + h2_), pf_.v, o0);
                    o1 = mfma32(VF(1, K0_ * 2 + h2_), pf_.v, o1);
                    __builtin_amdgcn_s_setprio(0);
                }
            }
        }
        asm volatile("s_waitcnt lgkmcnt(0)" ::: "memory");
        FENCE; __builtin_amdgcn_s_barrier(); FENCE;  // reads of cur done; no vm drain
    }
#undef KF
#undef VF

    // epilogue: O^T[d][q]: q = q0+ql, d = dblk*32 + 8a + i + 4hi
    int bb = bh >> 4, h = bh & 15;
    float iv = 1.0f / li;
#pragma unroll
    for (int dblk = 0; dblk < 2; ++dblk) {
#pragma unroll
        for (int a = 0; a < 4; ++a) {
            u16x4 wv;
#pragma unroll
            for (int i = 0; i < 4; ++i)
                wv[i] = f2b((dblk ? o1[4 * a + i] : o0[4 * a + i]) * iv);
            int dq = dblk * 32 + 8 * a + 4 * hi;
            *(u16x4*)&Yb[((size_t)(bb * T_SEQ + q0 + ql)) * CDIM + h * HD + dq] = wv;
        }
    }
}

// ---------------- launch ----------------
extern "C" void kernel_launch(void* const* d_in, const int* in_sizes, int n_in,
                              void* d_out, int out_size, void* d_ws, size_t ws_size,
                              hipStream_t stream) {
    const float* x      = (const float*)d_in[0];
    const float* w_attn = (const float*)d_in[1];
    const float* b_attn = (const float*)d_in[2];
    const float* w_proj = (const float*)d_in[3];
    const float* b_proj = (const float*)d_in[4];
    float* out = (float*)d_out;

    // workspace layout (bytes):
    //   0         xb  : x bf16 [8192][1024]         16,777,216  (reused as yb)
    //   16777216  wTa : w_attn^T bf16 [3072][1024]   6,291,456
    //   23068672  wTp : w_proj^T bf16 [1024][1024]   2,097,152
    //   25165824  qb  : [64][2048][64] bf16         16,777,216  (pre-scaled by QSCALE)
    //   41943040  kb  : [64][2048][64] bf16         16,777,216
    //   58720256  vTb : [64][64][2048] bf16         16,777,216  (V^T, written by GEMM1)
    char* ws = (char*)d_ws;
    unsigned short* xb  = (unsigned short*)(ws);
    unsigned short* wTa = (unsigned short*)(ws + 16777216);
    unsigned short* wTp = (unsigned short*)(ws + 23068672);
    unsigned short* qb  = (unsigned short*)(ws + 25165824);
    unsigned short* kb  = (unsigned short*)(ws + 41943040);
    unsigned short* vTb = (unsigned short*)(ws + 58720256);
    unsigned short* yb  = xb;  // alias: xb dead after GEMM1

    // fused prep: blocks [0,1024)=cast, [1024,4096)=w_attn^T, [4096,5120)=w_proj^T
    prep_kernel<<<dim3(5120), 256, 0, stream>>>(x, w_attn, w_proj, xb, wTa, wTp);

    // QKV GEMM: 1536 blocks, 24KB LDS -> 6 blocks/CU
    gemm_qkv_kernel<<<dim3(3072 / 128, 8192 / 128), 256, 0, stream>>>(
        xb, wTa, b_attn, qb, kb, vTb, 8192, 3072, 1024);

    // flash attention: 512 blocks x 8 waves (256 q-rows each), 2 blocks/CU
    attn32_kernel<<<dim3(512), 512, 0, stream>>>(qb, kb, vTb, yb);

    // proj GEMM -> fp32 out
    gemm_proj_kernel<<<dim3(1024 / 128, 8192 / 128), 256, 0, stream>>>(
        yb, wTp, b_proj, out, 8192, 1024, 1024);
}